// Round 1
// baseline (4779.064 us; speedup 1.0000x reference)
//
#include <hip/hip_runtime.h>
#include <hip/hip_bf16.h>

// ---------------------------------------------------------------------------
// GIN network forward on MI355X.
// Structure:
//   1. Build CSR (by dst) on device: count -> scan -> scatter.
//   2. Per layer: aggregate (z = h + sum_{j->i} h_j), GEMM1+bias+BN+ReLU,
//      GEMM2+bias+BN(+ReLU except last).
//   3. Fused mean-pool (binary search on sorted batch) + classifier.
// All fp32 baseline (round 0: correctness first; MFMA comes later).
// ---------------------------------------------------------------------------

#define N_NODES 50000
#define N_EDGES 200000
#define IN_DIM 64
#define EMB 300
#define HID 600           // 2*EMB
#define N_GRAPHS 1024
#define N_CLASS 10
#define BN_EPS 1e-5f

// ---------------- CSR build ----------------

__global__ void count_deg_kernel(const int* __restrict__ dst, int* __restrict__ deg, int E) {
    int e = blockIdx.x * blockDim.x + threadIdx.x;
    if (e < E) atomicAdd(&deg[dst[e]], 1);
}

// single-block exclusive scan over n ints (n ~ 50000), out has n+1 entries
__global__ void exclusive_scan_kernel(const int* __restrict__ in, int* __restrict__ out, int n) {
    __shared__ int sdata[1024];
    __shared__ int s_carry;
    const int tid = threadIdx.x;
    if (tid == 0) s_carry = 0;
    __syncthreads();
    for (int base = 0; base < n; base += 1024) {
        int idx = base + tid;
        int v = (idx < n) ? in[idx] : 0;
        sdata[tid] = v;
        __syncthreads();
        #pragma unroll
        for (int off = 1; off < 1024; off <<= 1) {
            int t = (tid >= off) ? sdata[tid - off] : 0;
            __syncthreads();
            sdata[tid] += t;
            __syncthreads();
        }
        int incl = sdata[tid];
        int carry = s_carry;
        if (idx < n) out[idx] = carry + incl - v;
        __syncthreads();                   // everyone done reading s_carry
        if (tid == 0) s_carry = carry + sdata[1023];
        __syncthreads();                   // new s_carry visible; sdata reusable
    }
    if (tid == 0) out[n] = s_carry;
}

__global__ void scatter_edges_kernel(const int* __restrict__ src, const int* __restrict__ dst,
                                     int* __restrict__ cursor, int* __restrict__ esrc, int E) {
    int e = blockIdx.x * blockDim.x + threadIdx.x;
    if (e < E) {
        int d = dst[e];
        int pos = atomicAdd(&cursor[d], 1);
        esrc[pos] = src[e];
    }
}

// ---------------- aggregation: z[i] = h[i] + sum_{e: dst=i} h[src_e] ----------------

__global__ void aggregate_kernel(const float* __restrict__ h, const int* __restrict__ row_ptr,
                                 const int* __restrict__ esrc, float* __restrict__ z,
                                 int n, int dim) {
    int i = blockIdx.x;
    int t = threadIdx.x;
    int s0 = row_ptr[i], s1 = row_ptr[i + 1];
    for (int d = t; d < dim; d += 64) {
        float acc = h[(size_t)i * dim + d];
        for (int e = s0; e < s1; ++e) {
            int s = esrc[e];
            acc += h[(size_t)s * dim + d];
        }
        z[(size_t)i * dim + d] = acc;
    }
}

// ---------------- GEMM + bias + BN (+ReLU) ----------------
// C[M,N] = epilogue(A[M,K] @ W[K,N] + bias), epilogue = BN(running stats) [+ ReLU]

#define BM 64
#define BN_T 64
#define BK 16

__global__ __launch_bounds__(256) void gemm_bias_bn_kernel(
        const float* __restrict__ A, const float* __restrict__ W,
        const float* __restrict__ bias,
        const float* __restrict__ gn, const float* __restrict__ bb,
        const float* __restrict__ bm, const float* __restrict__ bv,
        float* __restrict__ C, int M, int N, int K, int do_relu) {
    __shared__ float As[BM][BK + 1];
    __shared__ float Bs[BK][BN_T + 1];
    const int tid = threadIdx.x;
    const int tx = tid & 15;        // 0..15 -> 4 cols each
    const int ty = tid >> 4;        // 0..15 -> 4 rows each
    const int bm0 = blockIdx.x * BM;
    const int bn0 = blockIdx.y * BN_T;

    float acc[4][4] = {};

    for (int k0 = 0; k0 < K; k0 += BK) {
        // A tile: 64x16 (256 threads, 4 each)
        {
            int c = tid & 15;
            int r = tid >> 4;
            #pragma unroll
            for (int i = 0; i < 4; ++i) {
                int row = bm0 + r + i * 16;
                int col = k0 + c;
                As[r + i * 16][c] = (row < M && col < K) ? A[(size_t)row * K + col] : 0.f;
            }
        }
        // B tile: 16x64
        {
            int c = tid & 63;
            int r = tid >> 6;   // 0..3
            #pragma unroll
            for (int i = 0; i < 4; ++i) {
                int row = k0 + r + i * 4;
                int col = bn0 + c;
                Bs[r + i * 4][c] = (row < K && col < N) ? W[(size_t)row * N + col] : 0.f;
            }
        }
        __syncthreads();
        #pragma unroll
        for (int k = 0; k < BK; ++k) {
            float a[4], b[4];
            #pragma unroll
            for (int i = 0; i < 4; ++i) a[i] = As[ty * 4 + i][k];
            #pragma unroll
            for (int j = 0; j < 4; ++j) b[j] = Bs[k][tx * 4 + j];
            #pragma unroll
            for (int i = 0; i < 4; ++i)
                #pragma unroll
                for (int j = 0; j < 4; ++j) acc[i][j] += a[i] * b[j];
        }
        __syncthreads();
    }

    #pragma unroll
    for (int i = 0; i < 4; ++i) {
        int row = bm0 + ty * 4 + i;
        if (row >= M) continue;
        #pragma unroll
        for (int j = 0; j < 4; ++j) {
            int col = bn0 + tx * 4 + j;
            if (col >= N) continue;
            float t = acc[i][j] + bias[col];
            float s = gn[col] * rsqrtf(bv[col] + BN_EPS);
            float y = (t - bm[col]) * s + bb[col];
            if (do_relu) y = fmaxf(y, 0.f);
            C[(size_t)row * N + col] = y;
        }
    }
}

// ---------------- mean pool per graph + classifier ----------------

__global__ void pool_classify_kernel(const float* __restrict__ h, const int* __restrict__ batch,
                                     const float* __restrict__ clfW, const float* __restrict__ clfb,
                                     float* __restrict__ out, int n) {
    int g = blockIdx.x;
    __shared__ int s_lo, s_hi;
    __shared__ float pooled[EMB];
    if (threadIdx.x == 0) {
        int lo = 0, hi = n;
        while (lo < hi) { int mid = (lo + hi) >> 1; if (batch[mid] < g) lo = mid + 1; else hi = mid; }
        s_lo = lo;
        int lo2 = lo, hi2 = n;
        while (lo2 < hi2) { int mid = (lo2 + hi2) >> 1; if (batch[mid] < g + 1) lo2 = mid + 1; else hi2 = mid; }
        s_hi = lo2;
    }
    __syncthreads();
    const int lo = s_lo, hi = s_hi;
    const float inv = 1.0f / fmaxf((float)(hi - lo), 1.0f);
    for (int d = threadIdx.x; d < EMB; d += 64) {
        float a = 0.f;
        for (int r = lo; r < hi; ++r) a += h[(size_t)r * EMB + d];
        pooled[d] = a * inv;
    }
    __syncthreads();
    const int lane = threadIdx.x & 63;
    for (int c = 0; c < N_CLASS; ++c) {
        float p = 0.f;
        for (int d = lane; d < EMB; d += 64) p += pooled[d] * clfW[d * N_CLASS + c];
        #pragma unroll
        for (int off = 32; off > 0; off >>= 1) p += __shfl_down(p, off);
        if (lane == 0) out[g * N_CLASS + c] = p + clfb[c];
    }
}

// ---------------- launch ----------------

extern "C" void kernel_launch(void* const* d_in, const int* in_sizes, int n_in,
                              void* d_out, int out_size, void* d_ws, size_t ws_size,
                              hipStream_t stream) {
    const float* x      = (const float*)d_in[0];
    const int*   ei     = (const int*)d_in[1];
    const int*   batch  = (const int*)d_in[2];
    const float* l1_W1  = (const float*)d_in[3];
    const float* l1_b1  = (const float*)d_in[4];
    const float* l1_bn_g = (const float*)d_in[5];
    const float* l1_bn_b = (const float*)d_in[6];
    const float* l1_bn_m = (const float*)d_in[7];
    const float* l1_bn_v = (const float*)d_in[8];
    const float* l1_W2  = (const float*)d_in[9];
    const float* l1_b2  = (const float*)d_in[10];
    const float* l1_bno_g = (const float*)d_in[11];
    const float* l1_bno_b = (const float*)d_in[12];
    const float* l1_bno_m = (const float*)d_in[13];
    const float* l1_bno_v = (const float*)d_in[14];
    const float* Ws1    = (const float*)d_in[15];
    const float* bs1    = (const float*)d_in[16];
    const float* bn_g   = (const float*)d_in[17];
    const float* bn_b   = (const float*)d_in[18];
    const float* bn_m   = (const float*)d_in[19];
    const float* bn_v   = (const float*)d_in[20];
    const float* Ws2    = (const float*)d_in[21];
    const float* bs2    = (const float*)d_in[22];
    const float* bno_g  = (const float*)d_in[23];
    const float* bno_b  = (const float*)d_in[24];
    const float* bno_m  = (const float*)d_in[25];
    const float* bno_v  = (const float*)d_in[26];
    const float* clfW   = (const float*)d_in[27];
    const float* clfb   = (const float*)d_in[28];
    float* out = (float*)d_out;

    const int N = N_NODES, E = N_EDGES;
    const int* src = ei;
    const int* dst = ei + E;

    // workspace layout
    char* ws = (char*)d_ws;
    size_t off = 0;
    auto alloc = [&](size_t bytes) -> void* {
        void* p = ws + off;
        off += (bytes + 255) & ~(size_t)255;
        return p;
    };
    float* zmid   = (float*)alloc((size_t)N * HID * sizeof(float));   // 120 MB
    float* hbuf   = (float*)alloc((size_t)N * EMB * sizeof(float));   //  60 MB
    float* zin    = (float*)alloc((size_t)N * EMB * sizeof(float));   //  60 MB
    int*   deg    = (int*)alloc((size_t)N * sizeof(int));
    int*   rowptr = (int*)alloc((size_t)(N + 1) * sizeof(int));
    int*   cursor = (int*)alloc((size_t)N * sizeof(int));
    int*   esrc   = (int*)alloc((size_t)E * sizeof(int));
    (void)ws_size; (void)n_in; (void)in_sizes; (void)out_size;

    // ---- CSR build ----
    hipMemsetAsync(deg, 0, (size_t)N * sizeof(int), stream);
    count_deg_kernel<<<(E + 255) / 256, 256, 0, stream>>>(dst, deg, E);
    exclusive_scan_kernel<<<1, 1024, 0, stream>>>(deg, rowptr, N);
    hipMemcpyAsync(cursor, rowptr, (size_t)N * sizeof(int), hipMemcpyDeviceToDevice, stream);
    scatter_edges_kernel<<<(E + 255) / 256, 256, 0, stream>>>(src, dst, cursor, esrc, E);

    const int gm = (N + BM - 1) / BM;               // 782
    dim3 gridA(gm, (HID + BN_T - 1) / BN_T);        // N=600
    dim3 gridB(gm, (EMB + BN_T - 1) / BN_T);        // N=300

    // ---- layer 1 (64 -> 600 -> 300) ----
    aggregate_kernel<<<N, 64, 0, stream>>>(x, rowptr, esrc, zin, N, IN_DIM);
    gemm_bias_bn_kernel<<<gridA, 256, 0, stream>>>(
        zin, l1_W1, l1_b1, l1_bn_g, l1_bn_b, l1_bn_m, l1_bn_v,
        zmid, N, HID, IN_DIM, 1);
    gemm_bias_bn_kernel<<<gridB, 256, 0, stream>>>(
        zmid, l1_W2, l1_b2, l1_bno_g, l1_bno_b, l1_bno_m, l1_bno_v,
        hbuf, N, EMB, HID, 1);

    // ---- layers 2..5 (300 -> 600 -> 300) ----
    for (int i = 0; i < 4; ++i) {
        aggregate_kernel<<<N, 64, 0, stream>>>(hbuf, rowptr, esrc, zin, N, EMB);
        gemm_bias_bn_kernel<<<gridA, 256, 0, stream>>>(
            zin, Ws1 + (size_t)i * EMB * HID, bs1 + (size_t)i * HID,
            bn_g + (size_t)i * HID, bn_b + (size_t)i * HID,
            bn_m + (size_t)i * HID, bn_v + (size_t)i * HID,
            zmid, N, HID, EMB, 1);
        gemm_bias_bn_kernel<<<gridB, 256, 0, stream>>>(
            zmid, Ws2 + (size_t)i * HID * EMB, bs2 + (size_t)i * EMB,
            bno_g + (size_t)i * EMB, bno_b + (size_t)i * EMB,
            bno_m + (size_t)i * EMB, bno_v + (size_t)i * EMB,
            hbuf, N, EMB, HID, (i != 3) ? 1 : 0);
    }

    // ---- pool + classify ----
    pool_classify_kernel<<<N_GRAPHS, 64, 0, stream>>>(hbuf, batch, clfW, clfb, out, N);
}

// Round 2
// 770.007 us; speedup vs baseline: 6.2065x; 6.2065x over previous
//
#include <hip/hip_runtime.h>
#include <hip/hip_bf16.h>

// ---------------------------------------------------------------------------
// GIN forward, round 2: f16-input MFMA GEMMs (fp32 accumulate), padded dims.
//   EMB 300 -> 384, HID 600 -> 640, M 50000 -> 50048 (exact 128x128 tiles).
//   Weights converted once/call to f16 TRANSPOSED [N][K]; BN+bias folded to
//   y = acc*S[col] + T[col] with S=T=0 in pads so pad outputs are exactly 0.
// ---------------------------------------------------------------------------

#define N_NODES 50000
#define M_P     50048      // 391 * 128
#define N_EDGES 200000
#define IN_DIM  64
#define EMB     300
#define HID     600
#define EMB_P   384        // 3 * 128
#define HID_P   640        // 5 * 128
#define N_GRAPHS 1024
#define N_CLASS 10
#define BN_EPS  1e-5f

typedef _Float16 half8 __attribute__((ext_vector_type(8)));
typedef float    f32x4 __attribute__((ext_vector_type(4)));

__device__ __forceinline__ void gload16(const void* g, void* l) {
    __builtin_amdgcn_global_load_lds(
        (const __attribute__((address_space(1))) void*)g,
        (__attribute__((address_space(3))) void*)l, 16, 0, 0);
}

// ---------------- CSR build ----------------

__global__ void count_deg_kernel(const int* __restrict__ dst, int* __restrict__ deg, int E) {
    int e = blockIdx.x * blockDim.x + threadIdx.x;
    if (e < E) atomicAdd(&deg[dst[e]], 1);
}

__global__ void exclusive_scan_kernel(const int* __restrict__ in, int* __restrict__ out, int n) {
    __shared__ int sdata[1024];
    __shared__ int s_carry;
    const int tid = threadIdx.x;
    if (tid == 0) s_carry = 0;
    __syncthreads();
    for (int base = 0; base < n; base += 1024) {
        int idx = base + tid;
        int v = (idx < n) ? in[idx] : 0;
        sdata[tid] = v;
        __syncthreads();
        #pragma unroll
        for (int off = 1; off < 1024; off <<= 1) {
            int t = (tid >= off) ? sdata[tid - off] : 0;
            __syncthreads();
            sdata[tid] += t;
            __syncthreads();
        }
        int incl = sdata[tid];
        int carry = s_carry;
        if (idx < n) out[idx] = carry + incl - v;
        __syncthreads();
        if (tid == 0) s_carry = carry + sdata[1023];
        __syncthreads();
    }
    if (tid == 0) out[n] = s_carry;
}

__global__ void scatter_edges_kernel(const int* __restrict__ src, const int* __restrict__ dst,
                                     int* __restrict__ cursor, int* __restrict__ esrc, int E) {
    int e = blockIdx.x * blockDim.x + threadIdx.x;
    if (e < E) {
        int d = dst[e];
        int pos = atomicAdd(&cursor[d], 1);
        esrc[pos] = src[e];
    }
}

// ---------------- weight / epilogue-param conversion ----------------

// W [nb][K][N] fp32 -> Wt [nb][N_P][K_P] f16 (transposed + zero-padded)
__global__ void convert_w(const float* __restrict__ W, _Float16* __restrict__ Wt,
                          int K, int N, int K_P, int N_P) {
    int b = blockIdx.y;
    int i = blockIdx.x * 256 + threadIdx.x;
    if (i >= N_P * K_P) return;
    int n = i / K_P, k = i % K_P;
    _Float16 v = (_Float16)0.f;
    if (n < N && k < K) v = (_Float16)W[((size_t)b * K + k) * N + n];
    Wt[(size_t)b * N_P * K_P + i] = v;
}

// S = g*rsqrt(v+eps), T = (bias - m)*S + b ; pads -> 0 (output exactly 0)
__global__ void convert_st(const float* __restrict__ bias, const float* __restrict__ g,
                           const float* __restrict__ bb, const float* __restrict__ m,
                           const float* __restrict__ v, float* __restrict__ S,
                           float* __restrict__ T, int N, int N_P) {
    int b = blockIdx.y;
    int i = blockIdx.x * 256 + threadIdx.x;
    if (i >= N_P) return;
    float s = 0.f, t = 0.f;
    if (i < N) {
        s = g[b * N + i] * rsqrtf(v[b * N + i] + BN_EPS);
        t = (bias[b * N + i] - m[b * N + i]) * s + bb[b * N + i];
    }
    S[b * N_P + i] = s;
    T[b * N_P + i] = t;
}

// ---------------- aggregation ----------------

// f16 h [M_P][EMB_P] -> f16 z [M_P][EMB_P]; one 16B chunk per thread
__global__ void aggregate_f16(const _Float16* __restrict__ h, const int* __restrict__ rowptr,
                              const int* __restrict__ esrc, _Float16* __restrict__ z) {
    const int NCH = EMB_P / 8;          // 48
    const int NACT = 38;                // ceil(300/8); cols 300..303 are 0 in h
    int t = blockIdx.x * blockDim.x + threadIdx.x;
    int node = t / NCH;
    int c = t - node * NCH;
    if (node >= N_NODES) return;
    _Float16* zp = z + (size_t)node * EMB_P + c * 8;
    if (c >= NACT) {
        half8 zero = {};
        *(half8*)zp = zero;
        return;
    }
    float a[8];
    half8 v = *(const half8*)(h + (size_t)node * EMB_P + c * 8);
    #pragma unroll
    for (int j = 0; j < 8; ++j) a[j] = (float)v[j];
    int s0 = rowptr[node], s1 = rowptr[node + 1];
    for (int e = s0; e < s1; ++e) {
        half8 u = *(const half8*)(h + (size_t)esrc[e] * EMB_P + c * 8);
        #pragma unroll
        for (int j = 0; j < 8; ++j) a[j] += (float)u[j];
    }
    half8 o;
    #pragma unroll
    for (int j = 0; j < 8; ++j) o[j] = (_Float16)a[j];
    *(half8*)zp = o;
}

// layer-1: fp32 x [N][64] -> f16 z [M_P][64]; one float4 chunk per thread
__global__ void aggregate_f32in(const float* __restrict__ x, const int* __restrict__ rowptr,
                                const int* __restrict__ esrc, _Float16* __restrict__ z) {
    int t = blockIdx.x * blockDim.x + threadIdx.x;
    int node = t >> 4;
    int c = t & 15;
    if (node >= N_NODES) return;
    float4 a = *(const float4*)(x + (size_t)node * IN_DIM + c * 4);
    int s0 = rowptr[node], s1 = rowptr[node + 1];
    for (int e = s0; e < s1; ++e) {
        float4 u = *(const float4*)(x + (size_t)esrc[e] * IN_DIM + c * 4);
        a.x += u.x; a.y += u.y; a.z += u.z; a.w += u.w;
    }
    _Float16* zp = z + (size_t)node * IN_DIM + c * 4;
    zp[0] = (_Float16)a.x; zp[1] = (_Float16)a.y;
    zp[2] = (_Float16)a.z; zp[3] = (_Float16)a.w;
}

// ---------------- GEMM: C[M_P][N_P] = epi(A[M_P][K_P] @ Bt^T), f16 MFMA ----------------
// Bt is [N_P][K_P] (B transposed) so both frags are contiguous k.

__global__ __launch_bounds__(256) void gemm_f16_mfma(
        const _Float16* __restrict__ A, const _Float16* __restrict__ Bt,
        const float* __restrict__ Sc, const float* __restrict__ Tc,
        _Float16* __restrict__ C, int K_P, int N_P, int do_relu) {
    __shared__ _Float16 As[128 * 32];
    __shared__ _Float16 Bs[128 * 32];
    const int tid  = threadIdx.x;
    const int wid  = tid >> 6;
    const int lane = tid & 63;
    const size_t bm0 = (size_t)blockIdx.x * 128;
    const int    bn0 = blockIdx.y * 128;
    const int wr = (wid >> 1) * 64;          // wave tile 64x64
    const int wc = (wid & 1) * 64;

    // staging: wave w covers rows [w*16, w*16+16) and [64+w*16, ...)
    const int srow = wid * 16 + (lane >> 2);
    const int scol = (lane & 3) * 8;
    const _Float16* gA0 = A  + (bm0 + srow) * (size_t)K_P + scol;
    const _Float16* gA1 = gA0 + (size_t)64 * K_P;
    const _Float16* gB0 = Bt + ((size_t)bn0 + srow) * (size_t)K_P + scol;
    const _Float16* gB1 = gB0 + (size_t)64 * K_P;
    char* lA0 = (char*)As + wid * 1024; char* lA1 = lA0 + 4096;
    char* lB0 = (char*)Bs + wid * 1024; char* lB1 = lB0 + 4096;

    f32x4 acc[4][4];
    #pragma unroll
    for (int m = 0; m < 4; ++m)
        #pragma unroll
        for (int n = 0; n < 4; ++n) acc[m][n] = (f32x4){0.f, 0.f, 0.f, 0.f};

    const int fr = lane & 15;
    const int fc = (lane >> 4) * 8;

    for (int k0 = 0; k0 < K_P; k0 += 32) {
        gload16(gA0 + k0, lA0);
        gload16(gA1 + k0, lA1);
        gload16(gB0 + k0, lB0);
        gload16(gB1 + k0, lB1);
        __syncthreads();
        half8 af[4], bf[4];
        #pragma unroll
        for (int m = 0; m < 4; ++m)
            af[m] = *(const half8*)(As + (wr + m * 16 + fr) * 32 + fc);
        #pragma unroll
        for (int n = 0; n < 4; ++n)
            bf[n] = *(const half8*)(Bs + (wc + n * 16 + fr) * 32 + fc);
        #pragma unroll
        for (int m = 0; m < 4; ++m)
            #pragma unroll
            for (int n = 0; n < 4; ++n)
                acc[m][n] = __builtin_amdgcn_mfma_f32_16x16x32_f16(af[m], bf[n], acc[m][n], 0, 0, 0);
        __syncthreads();
    }

    // epilogue: y = acc*S[col] + T[col] (+ReLU), store f16
    #pragma unroll
    for (int n = 0; n < 4; ++n) {
        const int col = bn0 + wc + n * 16 + (lane & 15);
        const float s = Sc[col], t = Tc[col];
        #pragma unroll
        for (int m = 0; m < 4; ++m) {
            f32x4 v = acc[m][n];
            const size_t rbase = bm0 + wr + m * 16 + (lane >> 4) * 4;
            #pragma unroll
            for (int r = 0; r < 4; ++r) {
                float y = v[r] * s + t;
                if (do_relu) y = fmaxf(y, 0.f);
                C[(rbase + r) * (size_t)N_P + col] = (_Float16)y;
            }
        }
    }
}

// ---------------- mean pool + classifier ----------------

__global__ void pool_classify(const _Float16* __restrict__ h, const int* __restrict__ batch,
                              const float* __restrict__ clfW, const float* __restrict__ clfb,
                              float* __restrict__ out, int n) {
    int g = blockIdx.x;
    __shared__ int s_lo, s_hi;
    __shared__ float pooled[304];
    if (threadIdx.x == 0) {
        int lo = 0, hi = n;
        while (lo < hi) { int mid = (lo + hi) >> 1; if (batch[mid] < g) lo = mid + 1; else hi = mid; }
        s_lo = lo;
        int lo2 = lo, hi2 = n;
        while (lo2 < hi2) { int mid = (lo2 + hi2) >> 1; if (batch[mid] < g + 1) lo2 = mid + 1; else hi2 = mid; }
        s_hi = lo2;
    }
    __syncthreads();
    const int lo = s_lo, hi = s_hi;
    const float inv = 1.0f / fmaxf((float)(hi - lo), 1.0f);
    const int c = threadIdx.x;                 // chunk id
    if (c < 38) {
        float a[8] = {0.f, 0.f, 0.f, 0.f, 0.f, 0.f, 0.f, 0.f};
        for (int r = lo; r < hi; ++r) {
            half8 v = *(const half8*)(h + (size_t)r * EMB_P + c * 8);
            #pragma unroll
            for (int j = 0; j < 8; ++j) a[j] += (float)v[j];
        }
        #pragma unroll
        for (int j = 0; j < 8; ++j) pooled[c * 8 + j] = a[j] * inv;
    }
    __syncthreads();
    const int lane = threadIdx.x & 63;
    for (int cc = 0; cc < N_CLASS; ++cc) {
        float p = 0.f;
        for (int d = lane; d < EMB; d += 64) p += pooled[d] * clfW[d * N_CLASS + cc];
        #pragma unroll
        for (int off = 32; off > 0; off >>= 1) p += __shfl_down(p, off);
        if (lane == 0) out[g * N_CLASS + cc] = p + clfb[cc];
    }
}

// ---------------- launch ----------------

extern "C" void kernel_launch(void* const* d_in, const int* in_sizes, int n_in,
                              void* d_out, int out_size, void* d_ws, size_t ws_size,
                              hipStream_t stream) {
    const float* x      = (const float*)d_in[0];
    const int*   ei     = (const int*)d_in[1];
    const int*   batch  = (const int*)d_in[2];
    const float* l1_W1  = (const float*)d_in[3];
    const float* l1_b1  = (const float*)d_in[4];
    const float* l1_bn_g = (const float*)d_in[5];
    const float* l1_bn_b = (const float*)d_in[6];
    const float* l1_bn_m = (const float*)d_in[7];
    const float* l1_bn_v = (const float*)d_in[8];
    const float* l1_W2  = (const float*)d_in[9];
    const float* l1_b2  = (const float*)d_in[10];
    const float* l1_bno_g = (const float*)d_in[11];
    const float* l1_bno_b = (const float*)d_in[12];
    const float* l1_bno_m = (const float*)d_in[13];
    const float* l1_bno_v = (const float*)d_in[14];
    const float* Ws1    = (const float*)d_in[15];
    const float* bs1    = (const float*)d_in[16];
    const float* bn_g   = (const float*)d_in[17];
    const float* bn_b   = (const float*)d_in[18];
    const float* bn_m   = (const float*)d_in[19];
    const float* bn_v   = (const float*)d_in[20];
    const float* Ws2    = (const float*)d_in[21];
    const float* bs2    = (const float*)d_in[22];
    const float* bno_g  = (const float*)d_in[23];
    const float* bno_b  = (const float*)d_in[24];
    const float* bno_m  = (const float*)d_in[25];
    const float* bno_v  = (const float*)d_in[26];
    const float* clfW   = (const float*)d_in[27];
    const float* clfb   = (const float*)d_in[28];
    float* out = (float*)d_out;

    const int N = N_NODES, E = N_EDGES;
    const int* src = ei;
    const int* dst = ei + E;

    char* ws = (char*)d_ws;
    size_t off = 0;
    auto alloc = [&](size_t bytes) -> void* {
        void* p = ws + off;
        off += (bytes + 255) & ~(size_t)255;
        return p;
    };
    _Float16* zmid  = (_Float16*)alloc((size_t)M_P * HID_P * 2);   // 64 MB
    _Float16* hbuf  = (_Float16*)alloc((size_t)M_P * EMB_P * 2);   // 38 MB
    _Float16* zin   = (_Float16*)alloc((size_t)M_P * EMB_P * 2);   // 38 MB
    _Float16* wt_l1a = (_Float16*)alloc((size_t)HID_P * IN_DIM * 2);
    _Float16* wt_l1b = (_Float16*)alloc((size_t)EMB_P * HID_P * 2);
    _Float16* wt1   = (_Float16*)alloc((size_t)4 * HID_P * EMB_P * 2);
    _Float16* wt2   = (_Float16*)alloc((size_t)4 * EMB_P * HID_P * 2);
    float* s_l1a = (float*)alloc(HID_P * 4); float* t_l1a = (float*)alloc(HID_P * 4);
    float* s_l1b = (float*)alloc(EMB_P * 4); float* t_l1b = (float*)alloc(EMB_P * 4);
    float* s1 = (float*)alloc(4 * HID_P * 4); float* t1 = (float*)alloc(4 * HID_P * 4);
    float* s2 = (float*)alloc(4 * EMB_P * 4); float* t2 = (float*)alloc(4 * EMB_P * 4);
    int* deg    = (int*)alloc((size_t)N * 4);
    int* rowptr = (int*)alloc((size_t)(N + 1) * 4);
    int* cursor = (int*)alloc((size_t)N * 4);
    int* esrc   = (int*)alloc((size_t)E * 4);
    (void)ws_size; (void)n_in; (void)in_sizes; (void)out_size;

    // ---- CSR ----
    hipMemsetAsync(deg, 0, (size_t)N * 4, stream);
    count_deg_kernel<<<(E + 255) / 256, 256, 0, stream>>>(dst, deg, E);
    exclusive_scan_kernel<<<1, 1024, 0, stream>>>(deg, rowptr, N);
    hipMemcpyAsync(cursor, rowptr, (size_t)N * 4, hipMemcpyDeviceToDevice, stream);
    scatter_edges_kernel<<<(E + 255) / 256, 256, 0, stream>>>(src, dst, cursor, esrc, E);

    // ---- weight & epilogue-param conversion ----
    {
        dim3 g1((HID_P * IN_DIM + 255) / 256, 1);
        convert_w<<<g1, 256, 0, stream>>>(l1_W1, wt_l1a, IN_DIM, HID, IN_DIM, HID_P);
        dim3 g2((EMB_P * HID_P + 255) / 256, 1);
        convert_w<<<g2, 256, 0, stream>>>(l1_W2, wt_l1b, HID, EMB, HID_P, EMB_P);
        dim3 g3((HID_P * EMB_P + 255) / 256, 4);
        convert_w<<<g3, 256, 0, stream>>>(Ws1, wt1, EMB, HID, EMB_P, HID_P);
        dim3 g4((EMB_P * HID_P + 255) / 256, 4);
        convert_w<<<g4, 256, 0, stream>>>(Ws2, wt2, HID, EMB, HID_P, EMB_P);

        dim3 s1g((HID_P + 255) / 256, 1);
        convert_st<<<s1g, 256, 0, stream>>>(l1_b1, l1_bn_g, l1_bn_b, l1_bn_m, l1_bn_v, s_l1a, t_l1a, HID, HID_P);
        dim3 s2g((EMB_P + 255) / 256, 1);
        convert_st<<<s2g, 256, 0, stream>>>(l1_b2, l1_bno_g, l1_bno_b, l1_bno_m, l1_bno_v, s_l1b, t_l1b, EMB, EMB_P);
        dim3 s3g((HID_P + 255) / 256, 4);
        convert_st<<<s3g, 256, 0, stream>>>(bs1, bn_g, bn_b, bn_m, bn_v, s1, t1, HID, HID_P);
        dim3 s4g((EMB_P + 255) / 256, 4);
        convert_st<<<s4g, 256, 0, stream>>>(bs2, bno_g, bno_b, bno_m, bno_v, s2, t2, EMB, EMB_P);
    }

    const int gm = M_P / 128;                    // 391
    dim3 gridA(gm, HID_P / 128);                 // x640
    dim3 gridB(gm, EMB_P / 128);                 // x384

    // ---- layer 1 ----
    aggregate_f32in<<<(N * 16 + 255) / 256, 256, 0, stream>>>(x, rowptr, esrc, zin);
    gemm_f16_mfma<<<gridA, 256, 0, stream>>>(zin, wt_l1a, s_l1a, t_l1a, zmid, IN_DIM, HID_P, 1);
    gemm_f16_mfma<<<gridB, 256, 0, stream>>>(zmid, wt_l1b, s_l1b, t_l1b, hbuf, HID_P, EMB_P, 1);

    // ---- layers 2..5 ----
    for (int i = 0; i < 4; ++i) {
        aggregate_f16<<<(N * 48 + 255) / 256, 256, 0, stream>>>(hbuf, rowptr, esrc, zin);
        gemm_f16_mfma<<<gridA, 256, 0, stream>>>(
            zin, wt1 + (size_t)i * HID_P * EMB_P, s1 + i * HID_P, t1 + i * HID_P,
            zmid, EMB_P, HID_P, 1);
        gemm_f16_mfma<<<gridB, 256, 0, stream>>>(
            zmid, wt2 + (size_t)i * EMB_P * HID_P, s2 + i * EMB_P, t2 + i * EMB_P,
            hbuf, HID_P, EMB_P, (i != 3) ? 1 : 0);
    }

    // ---- pool + classify ----
    pool_classify<<<N_GRAPHS, 64, 0, stream>>>(hbuf, batch, clfW, clfb, out, N);
}

// Round 3
// 756.422 us; speedup vs baseline: 6.3180x; 1.0180x over previous
//
#include <hip/hip_runtime.h>
#include <hip/hip_bf16.h>

// ---------------------------------------------------------------------------
// GIN forward, round 3:
//   - multi-block scan for CSR rowptr (was 88us single-block)
//   - GEMM LDS in MFMA fragment order (conflict-free ds_read_b128, linear
//     global_load_lds; per-lane swizzle done on the GLOBAL source address)
//   - zin K-padding 320 instead of 384 (K needs x32 only) -> -17% on big GEMM1
// ---------------------------------------------------------------------------

#define N_NODES 50000
#define M_P     50048      // 391 * 128
#define N_EDGES 200000
#define IN_DIM  64
#define EMB     300
#define HID     600
#define EMB_P   384        // hbuf row stride / GEMM2 N (3 * 128)
#define EMB_K   320        // zin row stride / GEMM1 K (10 * 32)
#define HID_P   640        // 5 * 128
#define N_GRAPHS 1024
#define N_CLASS 10
#define BN_EPS  1e-5f

typedef _Float16 half8 __attribute__((ext_vector_type(8)));
typedef float    f32x4 __attribute__((ext_vector_type(4)));

__device__ __forceinline__ void gload16(const void* g, void* l) {
    __builtin_amdgcn_global_load_lds(
        (const __attribute__((address_space(1))) void*)g,
        (__attribute__((address_space(3))) void*)l, 16, 0, 0);
}

// ---------------- CSR build ----------------

__global__ void count_deg_kernel(const int* __restrict__ dst, int* __restrict__ deg, int E) {
    int e = blockIdx.x * blockDim.x + threadIdx.x;
    if (e < E) atomicAdd(&deg[dst[e]], 1);
}

// per-1024-chunk totals (grid = nb, 256 threads)
__global__ void block_reduce_kernel(const int* __restrict__ in, int* __restrict__ partials, int n) {
    __shared__ int sm[4];
    const int b = blockIdx.x, t = threadIdx.x;
    const int base = b * 1024;
    int v = 0;
    #pragma unroll
    for (int i = 0; i < 4; ++i) {
        int ix = base + t + i * 256;
        if (ix < n) v += in[ix];
    }
    #pragma unroll
    for (int off = 32; off > 0; off >>= 1) v += __shfl_xor(v, off);
    if ((t & 63) == 0) sm[t >> 6] = v;
    __syncthreads();
    if (t == 0) partials[b] = sm[0] + sm[1] + sm[2] + sm[3];
}

// exclusive scan of nb (<=64) partials, single wave
__global__ void scan_partials_kernel(int* __restrict__ partials, int nb) {
    const int t = threadIdx.x;
    int v = (t < nb) ? partials[t] : 0;
    const int orig = v;
    #pragma unroll
    for (int off = 1; off < 64; off <<= 1) {
        int u = __shfl_up(v, off);
        if (t >= off) v += u;
    }
    if (t < nb) partials[t] = v - orig;
}

// per-chunk scan + chunk offset (grid = nb, 1024 threads)
__global__ void block_scan_kernel(const int* __restrict__ in, const int* __restrict__ partials,
                                  int* __restrict__ out, int n, int total) {
    __shared__ int sd[1024];
    const int b = blockIdx.x, t = threadIdx.x;
    const int idx = b * 1024 + t;
    const int v = (idx < n) ? in[idx] : 0;
    sd[t] = v;
    __syncthreads();
    #pragma unroll
    for (int off = 1; off < 1024; off <<= 1) {
        int u = (t >= off) ? sd[t - off] : 0;
        __syncthreads();
        sd[t] += u;
        __syncthreads();
    }
    if (idx < n) out[idx] = partials[b] + sd[t] - v;
    if (b == 0 && t == 0) out[n] = total;
}

__global__ void scatter_edges_kernel(const int* __restrict__ src, const int* __restrict__ dst,
                                     int* __restrict__ cursor, int* __restrict__ esrc, int E) {
    int e = blockIdx.x * blockDim.x + threadIdx.x;
    if (e < E) {
        int d = dst[e];
        int pos = atomicAdd(&cursor[d], 1);
        esrc[pos] = src[e];
    }
}

// ---------------- weight / epilogue-param conversion ----------------

// W [nb][K][N] fp32 -> Wt [nb][N_P][K_P] f16 (transposed + zero-padded)
__global__ void convert_w(const float* __restrict__ W, _Float16* __restrict__ Wt,
                          int K, int N, int K_P, int N_P) {
    int b = blockIdx.y;
    int i = blockIdx.x * 256 + threadIdx.x;
    if (i >= N_P * K_P) return;
    int n = i / K_P, k = i % K_P;
    _Float16 v = (_Float16)0.f;
    if (n < N && k < K) v = (_Float16)W[((size_t)b * K + k) * N + n];
    Wt[(size_t)b * N_P * K_P + i] = v;
}

// S = g*rsqrt(v+eps), T = (bias - m)*S + b ; pads -> 0 (pad outputs exactly 0)
__global__ void convert_st(const float* __restrict__ bias, const float* __restrict__ g,
                           const float* __restrict__ bb, const float* __restrict__ m,
                           const float* __restrict__ v, float* __restrict__ S,
                           float* __restrict__ T, int N, int N_P) {
    int b = blockIdx.y;
    int i = blockIdx.x * 256 + threadIdx.x;
    if (i >= N_P) return;
    float s = 0.f, t = 0.f;
    if (i < N) {
        s = g[b * N + i] * rsqrtf(v[b * N + i] + BN_EPS);
        t = (bias[b * N + i] - m[b * N + i]) * s + bb[b * N + i];
    }
    S[b * N_P + i] = s;
    T[b * N_P + i] = t;
}

// ---------------- aggregation ----------------

// f16 h [M_P][EMB_P] -> f16 z [M_P][EMB_K]; one 16B chunk per thread
__global__ void aggregate_f16(const _Float16* __restrict__ h, const int* __restrict__ rowptr,
                              const int* __restrict__ esrc, _Float16* __restrict__ z) {
    const int NCH = EMB_K / 8;          // 40
    const int NACT = 38;                // ceil(300/8); h cols 300..383 are 0
    int t = blockIdx.x * blockDim.x + threadIdx.x;
    int node = t / NCH;
    int c = t - node * NCH;
    if (node >= N_NODES) return;
    _Float16* zp = z + (size_t)node * EMB_K + c * 8;
    if (c >= NACT) {
        half8 zero = {};
        *(half8*)zp = zero;
        return;
    }
    float a[8];
    half8 v = *(const half8*)(h + (size_t)node * EMB_P + c * 8);
    #pragma unroll
    for (int j = 0; j < 8; ++j) a[j] = (float)v[j];
    int s0 = rowptr[node], s1 = rowptr[node + 1];
    for (int e = s0; e < s1; ++e) {
        half8 u = *(const half8*)(h + (size_t)esrc[e] * EMB_P + c * 8);
        #pragma unroll
        for (int j = 0; j < 8; ++j) a[j] += (float)u[j];
    }
    half8 o;
    #pragma unroll
    for (int j = 0; j < 8; ++j) o[j] = (_Float16)a[j];
    *(half8*)zp = o;
}

// layer-1: fp32 x [N][64] -> f16 z [M_P][64]
__global__ void aggregate_f32in(const float* __restrict__ x, const int* __restrict__ rowptr,
                                const int* __restrict__ esrc, _Float16* __restrict__ z) {
    int t = blockIdx.x * blockDim.x + threadIdx.x;
    int node = t >> 4;
    int c = t & 15;
    if (node >= N_NODES) return;
    float4 a = *(const float4*)(x + (size_t)node * IN_DIM + c * 4);
    int s0 = rowptr[node], s1 = rowptr[node + 1];
    for (int e = s0; e < s1; ++e) {
        float4 u = *(const float4*)(x + (size_t)esrc[e] * IN_DIM + c * 4);
        a.x += u.x; a.y += u.y; a.z += u.z; a.w += u.w;
    }
    _Float16* zp = z + (size_t)node * IN_DIM + c * 4;
    zp[0] = (_Float16)a.x; zp[1] = (_Float16)a.y;
    zp[2] = (_Float16)a.z; zp[3] = (_Float16)a.w;
}

// ---------------- GEMM: C[M_P][N_P] = epi(A[M_P][K_P] @ Bt^T), f16 MFMA ----------------
// LDS holds 16x32 subtiles in MFMA FRAGMENT ORDER: subtile byte addr =
// sub*1024 + lane*16, where lane&15 = row-in-subtile, lane>>4 = k-slot.
// Staging writes are linear (global_load_lds), reads are linear ds_read_b128.

__global__ __launch_bounds__(256) void gemm_f16_mfma(
        const _Float16* __restrict__ A, const _Float16* __restrict__ Bt,
        const float* __restrict__ Sc, const float* __restrict__ Tc,
        _Float16* __restrict__ C, int K_P, int N_P, int do_relu) {
    __shared__ _Float16 As[128 * 32];    // 8 subtiles x 512 halves
    __shared__ _Float16 Bs[128 * 32];
    const int tid  = threadIdx.x;
    const int wid  = tid >> 6;
    const int lane = tid & 63;
    const size_t bm0 = (size_t)blockIdx.x * 128;
    const int    bn0 = blockIdx.y * 128;
    const int wr = (wid >> 1) * 64;
    const int wc = (wid & 1) * 64;

    // staging: lane l -> row_local l&15, k-slot l>>4 (fragment order)
    const int srow = lane & 15;
    const int scol = (lane >> 4) * 8;
    const _Float16* gA0 = A  + (bm0 + wid * 16 + srow) * (size_t)K_P + scol;
    const _Float16* gA1 = gA0 + (size_t)64 * K_P;
    const _Float16* gB0 = Bt + ((size_t)bn0 + wid * 16 + srow) * (size_t)K_P + scol;
    const _Float16* gB1 = gB0 + (size_t)64 * K_P;
    _Float16* lA0 = As + wid * 512;          // subtile wid
    _Float16* lA1 = As + (wid + 4) * 512;    // subtile wid+4
    _Float16* lB0 = Bs + wid * 512;
    _Float16* lB1 = Bs + (wid + 4) * 512;

    f32x4 acc[4][4];
    #pragma unroll
    for (int m = 0; m < 4; ++m)
        #pragma unroll
        for (int n = 0; n < 4; ++n) acc[m][n] = (f32x4){0.f, 0.f, 0.f, 0.f};

    const int subA = (wr >> 4);              // 0 or 4
    const int subB = (wc >> 4);

    for (int k0 = 0; k0 < K_P; k0 += 32) {
        gload16(gA0 + k0, lA0);
        gload16(gA1 + k0, lA1);
        gload16(gB0 + k0, lB0);
        gload16(gB1 + k0, lB1);
        __syncthreads();
        half8 af[4], bf[4];
        #pragma unroll
        for (int m = 0; m < 4; ++m)
            af[m] = *(const half8*)(As + (subA + m) * 512 + lane * 8);
        #pragma unroll
        for (int n = 0; n < 4; ++n)
            bf[n] = *(const half8*)(Bs + (subB + n) * 512 + lane * 8);
        #pragma unroll
        for (int m = 0; m < 4; ++m)
            #pragma unroll
            for (int n = 0; n < 4; ++n)
                acc[m][n] = __builtin_amdgcn_mfma_f32_16x16x32_f16(af[m], bf[n], acc[m][n], 0, 0, 0);
        __syncthreads();
    }

    #pragma unroll
    for (int n = 0; n < 4; ++n) {
        const int col = bn0 + wc + n * 16 + (lane & 15);
        const float s = Sc[col], t = Tc[col];
        #pragma unroll
        for (int m = 0; m < 4; ++m) {
            f32x4 v = acc[m][n];
            const size_t rbase = bm0 + wr + m * 16 + (lane >> 4) * 4;
            #pragma unroll
            for (int r = 0; r < 4; ++r) {
                float y = v[r] * s + t;
                if (do_relu) y = fmaxf(y, 0.f);
                C[(rbase + r) * (size_t)N_P + col] = (_Float16)y;
            }
        }
    }
}

// ---------------- mean pool + classifier ----------------

__global__ void pool_classify(const _Float16* __restrict__ h, const int* __restrict__ batch,
                              const float* __restrict__ clfW, const float* __restrict__ clfb,
                              float* __restrict__ out, int n) {
    int g = blockIdx.x;
    __shared__ int s_lo, s_hi;
    __shared__ float pooled[304];
    if (threadIdx.x == 0) {
        int lo = 0, hi = n;
        while (lo < hi) { int mid = (lo + hi) >> 1; if (batch[mid] < g) lo = mid + 1; else hi = mid; }
        s_lo = lo;
        int lo2 = lo, hi2 = n;
        while (lo2 < hi2) { int mid = (lo2 + hi2) >> 1; if (batch[mid] < g + 1) lo2 = mid + 1; else hi2 = mid; }
        s_hi = lo2;
    }
    __syncthreads();
    const int lo = s_lo, hi = s_hi;
    const float inv = 1.0f / fmaxf((float)(hi - lo), 1.0f);
    const int c = threadIdx.x;
    if (c < 38) {
        float a[8] = {0.f, 0.f, 0.f, 0.f, 0.f, 0.f, 0.f, 0.f};
        for (int r = lo; r < hi; ++r) {
            half8 v = *(const half8*)(h + (size_t)r * EMB_P + c * 8);
            #pragma unroll
            for (int j = 0; j < 8; ++j) a[j] += (float)v[j];
        }
        #pragma unroll
        for (int j = 0; j < 8; ++j) pooled[c * 8 + j] = a[j] * inv;
    }
    __syncthreads();
    const int lane = threadIdx.x & 63;
    for (int cc = 0; cc < N_CLASS; ++cc) {
        float p = 0.f;
        for (int d = lane; d < EMB; d += 64) p += pooled[d] * clfW[d * N_CLASS + cc];
        #pragma unroll
        for (int off = 32; off > 0; off >>= 1) p += __shfl_down(p, off);
        if (lane == 0) out[g * N_CLASS + cc] = p + clfb[cc];
    }
}

// ---------------- launch ----------------

extern "C" void kernel_launch(void* const* d_in, const int* in_sizes, int n_in,
                              void* d_out, int out_size, void* d_ws, size_t ws_size,
                              hipStream_t stream) {
    const float* x      = (const float*)d_in[0];
    const int*   ei     = (const int*)d_in[1];
    const int*   batch  = (const int*)d_in[2];
    const float* l1_W1  = (const float*)d_in[3];
    const float* l1_b1  = (const float*)d_in[4];
    const float* l1_bn_g = (const float*)d_in[5];
    const float* l1_bn_b = (const float*)d_in[6];
    const float* l1_bn_m = (const float*)d_in[7];
    const float* l1_bn_v = (const float*)d_in[8];
    const float* l1_W2  = (const float*)d_in[9];
    const float* l1_b2  = (const float*)d_in[10];
    const float* l1_bno_g = (const float*)d_in[11];
    const float* l1_bno_b = (const float*)d_in[12];
    const float* l1_bno_m = (const float*)d_in[13];
    const float* l1_bno_v = (const float*)d_in[14];
    const float* Ws1    = (const float*)d_in[15];
    const float* bs1    = (const float*)d_in[16];
    const float* bn_g   = (const float*)d_in[17];
    const float* bn_b   = (const float*)d_in[18];
    const float* bn_m   = (const float*)d_in[19];
    const float* bn_v   = (const float*)d_in[20];
    const float* Ws2    = (const float*)d_in[21];
    const float* bs2    = (const float*)d_in[22];
    const float* bno_g  = (const float*)d_in[23];
    const float* bno_b  = (const float*)d_in[24];
    const float* bno_m  = (const float*)d_in[25];
    const float* bno_v  = (const float*)d_in[26];
    const float* clfW   = (const float*)d_in[27];
    const float* clfb   = (const float*)d_in[28];
    float* out = (float*)d_out;

    const int N = N_NODES, E = N_EDGES;
    const int* src = ei;
    const int* dst = ei + E;

    char* ws = (char*)d_ws;
    size_t off = 0;
    auto alloc = [&](size_t bytes) -> void* {
        void* p = ws + off;
        off += (bytes + 255) & ~(size_t)255;
        return p;
    };
    _Float16* zmid  = (_Float16*)alloc((size_t)M_P * HID_P * 2);   // 64 MB
    _Float16* hbuf  = (_Float16*)alloc((size_t)M_P * EMB_P * 2);   // 38 MB
    _Float16* zin   = (_Float16*)alloc((size_t)M_P * EMB_K * 2);   // 32 MB
    _Float16* wt_l1a = (_Float16*)alloc((size_t)HID_P * IN_DIM * 2);
    _Float16* wt_l1b = (_Float16*)alloc((size_t)EMB_P * HID_P * 2);
    _Float16* wt1   = (_Float16*)alloc((size_t)4 * HID_P * EMB_K * 2);
    _Float16* wt2   = (_Float16*)alloc((size_t)4 * EMB_P * HID_P * 2);
    float* s_l1a = (float*)alloc(HID_P * 4); float* t_l1a = (float*)alloc(HID_P * 4);
    float* s_l1b = (float*)alloc(EMB_P * 4); float* t_l1b = (float*)alloc(EMB_P * 4);
    float* s1 = (float*)alloc(4 * HID_P * 4); float* t1 = (float*)alloc(4 * HID_P * 4);
    float* s2 = (float*)alloc(4 * EMB_P * 4); float* t2 = (float*)alloc(4 * EMB_P * 4);
    int* deg      = (int*)alloc((size_t)N * 4);
    int* rowptr   = (int*)alloc((size_t)(N + 1) * 4);
    int* cursor   = (int*)alloc((size_t)N * 4);
    int* esrc     = (int*)alloc((size_t)E * 4);
    int* partials = (int*)alloc(64 * 4);
    (void)ws_size; (void)n_in; (void)in_sizes; (void)out_size;

    const int NB_SCAN = (N + 1023) / 1024;   // 49

    // ---- CSR ----
    hipMemsetAsync(deg, 0, (size_t)N * 4, stream);
    count_deg_kernel<<<(E + 255) / 256, 256, 0, stream>>>(dst, deg, E);
    block_reduce_kernel<<<NB_SCAN, 256, 0, stream>>>(deg, partials, N);
    scan_partials_kernel<<<1, 64, 0, stream>>>(partials, NB_SCAN);
    block_scan_kernel<<<NB_SCAN, 1024, 0, stream>>>(deg, partials, rowptr, N, E);
    hipMemcpyAsync(cursor, rowptr, (size_t)N * 4, hipMemcpyDeviceToDevice, stream);
    scatter_edges_kernel<<<(E + 255) / 256, 256, 0, stream>>>(src, dst, cursor, esrc, E);

    // ---- weight & epilogue-param conversion ----
    {
        dim3 g1((HID_P * IN_DIM + 255) / 256, 1);
        convert_w<<<g1, 256, 0, stream>>>(l1_W1, wt_l1a, IN_DIM, HID, IN_DIM, HID_P);
        dim3 g2((EMB_P * HID_P + 255) / 256, 1);
        convert_w<<<g2, 256, 0, stream>>>(l1_W2, wt_l1b, HID, EMB, HID_P, EMB_P);
        dim3 g3((HID_P * EMB_K + 255) / 256, 4);
        convert_w<<<g3, 256, 0, stream>>>(Ws1, wt1, EMB, HID, EMB_K, HID_P);
        dim3 g4((EMB_P * HID_P + 255) / 256, 4);
        convert_w<<<g4, 256, 0, stream>>>(Ws2, wt2, HID, EMB, HID_P, EMB_P);

        dim3 s1g((HID_P + 255) / 256, 1);
        convert_st<<<s1g, 256, 0, stream>>>(l1_b1, l1_bn_g, l1_bn_b, l1_bn_m, l1_bn_v, s_l1a, t_l1a, HID, HID_P);
        dim3 s2g((EMB_P + 255) / 256, 1);
        convert_st<<<s2g, 256, 0, stream>>>(l1_b2, l1_bno_g, l1_bno_b, l1_bno_m, l1_bno_v, s_l1b, t_l1b, EMB, EMB_P);
        dim3 s3g((HID_P + 255) / 256, 4);
        convert_st<<<s3g, 256, 0, stream>>>(bs1, bn_g, bn_b, bn_m, bn_v, s1, t1, HID, HID_P);
        dim3 s4g((EMB_P + 255) / 256, 4);
        convert_st<<<s4g, 256, 0, stream>>>(bs2, bno_g, bno_b, bno_m, bno_v, s2, t2, EMB, EMB_P);
    }

    const int gm = M_P / 128;                    // 391
    dim3 gridA(gm, HID_P / 128);                 // N=640
    dim3 gridB(gm, EMB_P / 128);                 // N=384

    // ---- layer 1 ----
    aggregate_f32in<<<(N * 16 + 255) / 256, 256, 0, stream>>>(x, rowptr, esrc, zin);
    gemm_f16_mfma<<<gridA, 256, 0, stream>>>(zin, wt_l1a, s_l1a, t_l1a, zmid, IN_DIM, HID_P, 1);
    gemm_f16_mfma<<<gridB, 256, 0, stream>>>(zmid, wt_l1b, s_l1b, t_l1b, hbuf, HID_P, EMB_P, 1);

    // ---- layers 2..5 ----
    for (int i = 0; i < 4; ++i) {
        aggregate_f16<<<(N * (EMB_K / 8) + 255) / 256, 256, 0, stream>>>(hbuf, rowptr, esrc, zin);
        gemm_f16_mfma<<<gridA, 256, 0, stream>>>(
            zin, wt1 + (size_t)i * HID_P * EMB_K, s1 + i * HID_P, t1 + i * HID_P,
            zmid, EMB_K, HID_P, 1);
        gemm_f16_mfma<<<gridB, 256, 0, stream>>>(
            zmid, wt2 + (size_t)i * EMB_P * HID_P, s2 + i * EMB_P, t2 + i * EMB_P,
            hbuf, HID_P, EMB_P, (i != 3) ? 1 : 0);
    }

    // ---- pool + classify ----
    pool_classify<<<N_GRAPHS, 64, 0, stream>>>(hbuf, batch, clfW, clfb, out, N);
}

// Round 4
// 743.911 us; speedup vs baseline: 6.4242x; 1.0168x over previous
//
#include <hip/hip_runtime.h>
#include <hip/hip_bf16.h>

// ---------------------------------------------------------------------------
// GIN forward, round 4:
//   - GEMM K-loop: 3-buffer LDS pipeline, 2 stages in flight, counted
//     s_waitcnt vmcnt(8/4/0) + raw s_barrier (no vmcnt(0) drain in main loop).
//     Round-3 structure (vmcnt(0)+__syncthreads per K-step) was latency-bound:
//     MfmaUtil 13.7%, occupancy 22%, 367 TF. (T3/T4 from the technique catalog)
//   - everything else unchanged from round 3 (passed, absmax 0.5).
// ---------------------------------------------------------------------------

#define N_NODES 50000
#define M_P     50048      // 391 * 128
#define N_EDGES 200000
#define IN_DIM  64
#define EMB     300
#define HID     600
#define EMB_P   384        // hbuf row stride / GEMM2 N (3 * 128)
#define EMB_K   320        // zin row stride / GEMM1 K (10 * 32)
#define HID_P   640        // 5 * 128
#define N_GRAPHS 1024
#define N_CLASS 10
#define BN_EPS  1e-5f

typedef _Float16 half8 __attribute__((ext_vector_type(8)));
typedef float    f32x4 __attribute__((ext_vector_type(4)));

__device__ __forceinline__ void gload16(const void* g, void* l) {
    __builtin_amdgcn_global_load_lds(
        (const __attribute__((address_space(1))) void*)g,
        (__attribute__((address_space(3))) void*)l, 16, 0, 0);
}

// ---------------- CSR build ----------------

__global__ void count_deg_kernel(const int* __restrict__ dst, int* __restrict__ deg, int E) {
    int e = blockIdx.x * blockDim.x + threadIdx.x;
    if (e < E) atomicAdd(&deg[dst[e]], 1);
}

__global__ void block_reduce_kernel(const int* __restrict__ in, int* __restrict__ partials, int n) {
    __shared__ int sm[4];
    const int b = blockIdx.x, t = threadIdx.x;
    const int base = b * 1024;
    int v = 0;
    #pragma unroll
    for (int i = 0; i < 4; ++i) {
        int ix = base + t + i * 256;
        if (ix < n) v += in[ix];
    }
    #pragma unroll
    for (int off = 32; off > 0; off >>= 1) v += __shfl_xor(v, off);
    if ((t & 63) == 0) sm[t >> 6] = v;
    __syncthreads();
    if (t == 0) partials[b] = sm[0] + sm[1] + sm[2] + sm[3];
}

__global__ void scan_partials_kernel(int* __restrict__ partials, int nb) {
    const int t = threadIdx.x;
    int v = (t < nb) ? partials[t] : 0;
    const int orig = v;
    #pragma unroll
    for (int off = 1; off < 64; off <<= 1) {
        int u = __shfl_up(v, off);
        if (t >= off) v += u;
    }
    if (t < nb) partials[t] = v - orig;
}

__global__ void block_scan_kernel(const int* __restrict__ in, const int* __restrict__ partials,
                                  int* __restrict__ out, int n, int total) {
    __shared__ int sd[1024];
    const int b = blockIdx.x, t = threadIdx.x;
    const int idx = b * 1024 + t;
    const int v = (idx < n) ? in[idx] : 0;
    sd[t] = v;
    __syncthreads();
    #pragma unroll
    for (int off = 1; off < 1024; off <<= 1) {
        int u = (t >= off) ? sd[t - off] : 0;
        __syncthreads();
        sd[t] += u;
        __syncthreads();
    }
    if (idx < n) out[idx] = partials[b] + sd[t] - v;
    if (b == 0 && t == 0) out[n] = total;
}

__global__ void scatter_edges_kernel(const int* __restrict__ src, const int* __restrict__ dst,
                                     int* __restrict__ cursor, int* __restrict__ esrc, int E) {
    int e = blockIdx.x * blockDim.x + threadIdx.x;
    if (e < E) {
        int d = dst[e];
        int pos = atomicAdd(&cursor[d], 1);
        esrc[pos] = src[e];
    }
}

// ---------------- weight / epilogue-param conversion ----------------

__global__ void convert_w(const float* __restrict__ W, _Float16* __restrict__ Wt,
                          int K, int N, int K_P, int N_P) {
    int b = blockIdx.y;
    int i = blockIdx.x * 256 + threadIdx.x;
    if (i >= N_P * K_P) return;
    int n = i / K_P, k = i % K_P;
    _Float16 v = (_Float16)0.f;
    if (n < N && k < K) v = (_Float16)W[((size_t)b * K + k) * N + n];
    Wt[(size_t)b * N_P * K_P + i] = v;
}

__global__ void convert_st(const float* __restrict__ bias, const float* __restrict__ g,
                           const float* __restrict__ bb, const float* __restrict__ m,
                           const float* __restrict__ v, float* __restrict__ S,
                           float* __restrict__ T, int N, int N_P) {
    int b = blockIdx.y;
    int i = blockIdx.x * 256 + threadIdx.x;
    if (i >= N_P) return;
    float s = 0.f, t = 0.f;
    if (i < N) {
        s = g[b * N + i] * rsqrtf(v[b * N + i] + BN_EPS);
        t = (bias[b * N + i] - m[b * N + i]) * s + bb[b * N + i];
    }
    S[b * N_P + i] = s;
    T[b * N_P + i] = t;
}

// ---------------- aggregation ----------------

__global__ void aggregate_f16(const _Float16* __restrict__ h, const int* __restrict__ rowptr,
                              const int* __restrict__ esrc, _Float16* __restrict__ z) {
    const int NCH = EMB_K / 8;          // 40
    const int NACT = 38;                // ceil(300/8); h cols 300..383 are 0
    int t = blockIdx.x * blockDim.x + threadIdx.x;
    int node = t / NCH;
    int c = t - node * NCH;
    if (node >= N_NODES) return;
    _Float16* zp = z + (size_t)node * EMB_K + c * 8;
    if (c >= NACT) {
        half8 zero = {};
        *(half8*)zp = zero;
        return;
    }
    float a[8];
    half8 v = *(const half8*)(h + (size_t)node * EMB_P + c * 8);
    #pragma unroll
    for (int j = 0; j < 8; ++j) a[j] = (float)v[j];
    int s0 = rowptr[node], s1 = rowptr[node + 1];
    for (int e = s0; e < s1; ++e) {
        half8 u = *(const half8*)(h + (size_t)esrc[e] * EMB_P + c * 8);
        #pragma unroll
        for (int j = 0; j < 8; ++j) a[j] += (float)u[j];
    }
    half8 o;
    #pragma unroll
    for (int j = 0; j < 8; ++j) o[j] = (_Float16)a[j];
    *(half8*)zp = o;
}

__global__ void aggregate_f32in(const float* __restrict__ x, const int* __restrict__ rowptr,
                                const int* __restrict__ esrc, _Float16* __restrict__ z) {
    int t = blockIdx.x * blockDim.x + threadIdx.x;
    int node = t >> 4;
    int c = t & 15;
    if (node >= N_NODES) return;
    float4 a = *(const float4*)(x + (size_t)node * IN_DIM + c * 4);
    int s0 = rowptr[node], s1 = rowptr[node + 1];
    for (int e = s0; e < s1; ++e) {
        float4 u = *(const float4*)(x + (size_t)esrc[e] * IN_DIM + c * 4);
        a.x += u.x; a.y += u.y; a.z += u.z; a.w += u.w;
    }
    _Float16* zp = z + (size_t)node * IN_DIM + c * 4;
    zp[0] = (_Float16)a.x; zp[1] = (_Float16)a.y;
    zp[2] = (_Float16)a.z; zp[3] = (_Float16)a.w;
}

// ---------------- GEMM: C[M_P][N_P] = epi(A[M_P][K_P] @ Bt^T), f16 MFMA ----------------
// LDS: 3 buffers x (A 128x32 + B 128x32) in MFMA fragment order.
// Pipeline: 2 stages in flight; per iter: stage(t+2) -> vmcnt(8) -> barrier ->
// ds_read+MFMA(buf t) -> barrier. vmcnt never drains to 0 in the main loop.

__global__ __launch_bounds__(256) void gemm_f16_mfma(
        const _Float16* __restrict__ A, const _Float16* __restrict__ Bt,
        const float* __restrict__ Sc, const float* __restrict__ Tc,
        _Float16* __restrict__ C, int K_P, int N_P, int do_relu) {
    __shared__ _Float16 As[3 * 4096];    // 3 bufs x 8 subtiles x 512 halves
    __shared__ _Float16 Bs[3 * 4096];
    const int tid  = threadIdx.x;
    const int wid  = tid >> 6;
    const int lane = tid & 63;
    const size_t bm0 = (size_t)blockIdx.x * 128;
    const int    bn0 = blockIdx.y * 128;
    const int wr = (wid >> 1) * 64;
    const int wc = (wid & 1) * 64;

    // staging: lane l -> row_local l&15, k-slot l>>4 (fragment order)
    const int srow = lane & 15;
    const int scol = (lane >> 4) * 8;
    const _Float16* gA0 = A  + (bm0 + wid * 16 + srow) * (size_t)K_P + scol;
    const _Float16* gA1 = gA0 + (size_t)64 * K_P;
    const _Float16* gB0 = Bt + ((size_t)bn0 + wid * 16 + srow) * (size_t)K_P + scol;
    const _Float16* gB1 = gB0 + (size_t)64 * K_P;
    _Float16* lA0 = As + wid * 512;          // subtile wid
    _Float16* lA1 = As + (wid + 4) * 512;    // subtile wid+4
    _Float16* lB0 = Bs + wid * 512;
    _Float16* lB1 = Bs + (wid + 4) * 512;

    f32x4 acc[4][4];
    #pragma unroll
    for (int m = 0; m < 4; ++m)
        #pragma unroll
        for (int n = 0; n < 4; ++n) acc[m][n] = (f32x4){0.f, 0.f, 0.f, 0.f};

    const int subA = (wr >> 4);              // 0 or 4
    const int subB = (wc >> 4);

    auto stage = [&](int buf, int k0) {
        const int o = buf * 4096;
        gload16(gA0 + k0, lA0 + o);
        gload16(gA1 + k0, lA1 + o);
        gload16(gB0 + k0, lB0 + o);
        gload16(gB1 + k0, lB1 + o);
    };
    auto compute = [&](int buf) {
        const _Float16* as = As + buf * 4096;
        const _Float16* bs = Bs + buf * 4096;
        half8 af[4], bf[4];
        #pragma unroll
        for (int m = 0; m < 4; ++m)
            af[m] = *(const half8*)(as + (subA + m) * 512 + lane * 8);
        #pragma unroll
        for (int n = 0; n < 4; ++n)
            bf[n] = *(const half8*)(bs + (subB + n) * 512 + lane * 8);
        #pragma unroll
        for (int m = 0; m < 4; ++m)
            #pragma unroll
            for (int n = 0; n < 4; ++n)
                acc[m][n] = __builtin_amdgcn_mfma_f32_16x16x32_f16(af[m], bf[n], acc[m][n], 0, 0, 0);
    };

    const int nt = K_P >> 5;                 // >= 2 for all our shapes
    stage(0, 0);
    stage(1, 32);
    int bc = 0;                              // compute-buffer index
    for (int t = 0; t + 2 < nt; ++t) {
        int bst = bc + 2; if (bst >= 3) bst -= 3;
        stage(bst, (t + 2) * 32);
        asm volatile("s_waitcnt vmcnt(8)" ::: "memory");   // oldest stage landed
        __builtin_amdgcn_s_barrier();                      // ..for ALL waves
        compute(bc);
        __builtin_amdgcn_s_barrier();                      // reads done before overwrite
        if (++bc == 3) bc = 0;
    }
    // t = nt-2: one stage still in flight behind the one we compute
    asm volatile("s_waitcnt vmcnt(4)" ::: "memory");
    __builtin_amdgcn_s_barrier();
    compute(bc);
    __builtin_amdgcn_s_barrier();
    if (++bc == 3) bc = 0;
    // t = nt-1: last buffer
    asm volatile("s_waitcnt vmcnt(0)" ::: "memory");
    __builtin_amdgcn_s_barrier();
    compute(bc);

    // epilogue: y = acc*S[col] + T[col] (+ReLU), store f16
    #pragma unroll
    for (int n = 0; n < 4; ++n) {
        const int col = bn0 + wc + n * 16 + (lane & 15);
        const float s = Sc[col], t = Tc[col];
        #pragma unroll
        for (int m = 0; m < 4; ++m) {
            f32x4 v = acc[m][n];
            const size_t rbase = bm0 + wr + m * 16 + (lane >> 4) * 4;
            #pragma unroll
            for (int r = 0; r < 4; ++r) {
                float y = v[r] * s + t;
                if (do_relu) y = fmaxf(y, 0.f);
                C[(rbase + r) * (size_t)N_P + col] = (_Float16)y;
            }
        }
    }
}

// ---------------- mean pool + classifier ----------------

__global__ void pool_classify(const _Float16* __restrict__ h, const int* __restrict__ batch,
                              const float* __restrict__ clfW, const float* __restrict__ clfb,
                              float* __restrict__ out, int n) {
    int g = blockIdx.x;
    __shared__ int s_lo, s_hi;
    __shared__ float pooled[304];
    if (threadIdx.x == 0) {
        int lo = 0, hi = n;
        while (lo < hi) { int mid = (lo + hi) >> 1; if (batch[mid] < g) lo = mid + 1; else hi = mid; }
        s_lo = lo;
        int lo2 = lo, hi2 = n;
        while (lo2 < hi2) { int mid = (lo2 + hi2) >> 1; if (batch[mid] < g + 1) lo2 = mid + 1; else hi2 = mid; }
        s_hi = lo2;
    }
    __syncthreads();
    const int lo = s_lo, hi = s_hi;
    const float inv = 1.0f / fmaxf((float)(hi - lo), 1.0f);
    const int c = threadIdx.x;
    if (c < 38) {
        float a[8] = {0.f, 0.f, 0.f, 0.f, 0.f, 0.f, 0.f, 0.f};
        for (int r = lo; r < hi; ++r) {
            half8 v = *(const half8*)(h + (size_t)r * EMB_P + c * 8);
            #pragma unroll
            for (int j = 0; j < 8; ++j) a[j] += (float)v[j];
        }
        #pragma unroll
        for (int j = 0; j < 8; ++j) pooled[c * 8 + j] = a[j] * inv;
    }
    __syncthreads();
    const int lane = threadIdx.x & 63;
    for (int cc = 0; cc < N_CLASS; ++cc) {
        float p = 0.f;
        for (int d = lane; d < EMB; d += 64) p += pooled[d] * clfW[d * N_CLASS + cc];
        #pragma unroll
        for (int off = 32; off > 0; off >>= 1) p += __shfl_down(p, off);
        if (lane == 0) out[g * N_CLASS + cc] = p + clfb[cc];
    }
}

// ---------------- launch ----------------

extern "C" void kernel_launch(void* const* d_in, const int* in_sizes, int n_in,
                              void* d_out, int out_size, void* d_ws, size_t ws_size,
                              hipStream_t stream) {
    const float* x      = (const float*)d_in[0];
    const int*   ei     = (const int*)d_in[1];
    const int*   batch  = (const int*)d_in[2];
    const float* l1_W1  = (const float*)d_in[3];
    const float* l1_b1  = (const float*)d_in[4];
    const float* l1_bn_g = (const float*)d_in[5];
    const float* l1_bn_b = (const float*)d_in[6];
    const float* l1_bn_m = (const float*)d_in[7];
    const float* l1_bn_v = (const float*)d_in[8];
    const float* l1_W2  = (const float*)d_in[9];
    const float* l1_b2  = (const float*)d_in[10];
    const float* l1_bno_g = (const float*)d_in[11];
    const float* l1_bno_b = (const float*)d_in[12];
    const float* l1_bno_m = (const float*)d_in[13];
    const float* l1_bno_v = (const float*)d_in[14];
    const float* Ws1    = (const float*)d_in[15];
    const float* bs1    = (const float*)d_in[16];
    const float* bn_g   = (const float*)d_in[17];
    const float* bn_b   = (const float*)d_in[18];
    const float* bn_m   = (const float*)d_in[19];
    const float* bn_v   = (const float*)d_in[20];
    const float* Ws2    = (const float*)d_in[21];
    const float* bs2    = (const float*)d_in[22];
    const float* bno_g  = (const float*)d_in[23];
    const float* bno_b  = (const float*)d_in[24];
    const float* bno_m  = (const float*)d_in[25];
    const float* bno_v  = (const float*)d_in[26];
    const float* clfW   = (const float*)d_in[27];
    const float* clfb   = (const float*)d_in[28];
    float* out = (float*)d_out;

    const int N = N_NODES, E = N_EDGES;
    const int* src = ei;
    const int* dst = ei + E;

    char* ws = (char*)d_ws;
    size_t off = 0;
    auto alloc = [&](size_t bytes) -> void* {
        void* p = ws + off;
        off += (bytes + 255) & ~(size_t)255;
        return p;
    };
    _Float16* zmid  = (_Float16*)alloc((size_t)M_P * HID_P * 2);   // 64 MB
    _Float16* hbuf  = (_Float16*)alloc((size_t)M_P * EMB_P * 2);   // 38 MB
    _Float16* zin   = (_Float16*)alloc((size_t)M_P * EMB_K * 2);   // 32 MB
    _Float16* wt_l1a = (_Float16*)alloc((size_t)HID_P * IN_DIM * 2);
    _Float16* wt_l1b = (_Float16*)alloc((size_t)EMB_P * HID_P * 2);
    _Float16* wt1   = (_Float16*)alloc((size_t)4 * HID_P * EMB_K * 2);
    _Float16* wt2   = (_Float16*)alloc((size_t)4 * EMB_P * HID_P * 2);
    float* s_l1a = (float*)alloc(HID_P * 4); float* t_l1a = (float*)alloc(HID_P * 4);
    float* s_l1b = (float*)alloc(EMB_P * 4); float* t_l1b = (float*)alloc(EMB_P * 4);
    float* s1 = (float*)alloc(4 * HID_P * 4); float* t1 = (float*)alloc(4 * HID_P * 4);
    float* s2 = (float*)alloc(4 * EMB_P * 4); float* t2 = (float*)alloc(4 * EMB_P * 4);
    int* deg      = (int*)alloc((size_t)N * 4);
    int* rowptr   = (int*)alloc((size_t)(N + 1) * 4);
    int* cursor   = (int*)alloc((size_t)N * 4);
    int* esrc     = (int*)alloc((size_t)E * 4);
    int* partials = (int*)alloc(64 * 4);
    (void)ws_size; (void)n_in; (void)in_sizes; (void)out_size;

    const int NB_SCAN = (N + 1023) / 1024;   // 49

    // ---- CSR ----
    hipMemsetAsync(deg, 0, (size_t)N * 4, stream);
    count_deg_kernel<<<(E + 255) / 256, 256, 0, stream>>>(dst, deg, E);
    block_reduce_kernel<<<NB_SCAN, 256, 0, stream>>>(deg, partials, N);
    scan_partials_kernel<<<1, 64, 0, stream>>>(partials, NB_SCAN);
    block_scan_kernel<<<NB_SCAN, 1024, 0, stream>>>(deg, partials, rowptr, N, E);
    hipMemcpyAsync(cursor, rowptr, (size_t)N * 4, hipMemcpyDeviceToDevice, stream);
    scatter_edges_kernel<<<(E + 255) / 256, 256, 0, stream>>>(src, dst, cursor, esrc, E);

    // ---- weight & epilogue-param conversion ----
    {
        dim3 g1((HID_P * IN_DIM + 255) / 256, 1);
        convert_w<<<g1, 256, 0, stream>>>(l1_W1, wt_l1a, IN_DIM, HID, IN_DIM, HID_P);
        dim3 g2((EMB_P * HID_P + 255) / 256, 1);
        convert_w<<<g2, 256, 0, stream>>>(l1_W2, wt_l1b, HID, EMB, HID_P, EMB_P);
        dim3 g3((HID_P * EMB_K + 255) / 256, 4);
        convert_w<<<g3, 256, 0, stream>>>(Ws1, wt1, EMB, HID, EMB_K, HID_P);
        dim3 g4((EMB_P * HID_P + 255) / 256, 4);
        convert_w<<<g4, 256, 0, stream>>>(Ws2, wt2, HID, EMB, HID_P, EMB_P);

        dim3 s1g((HID_P + 255) / 256, 1);
        convert_st<<<s1g, 256, 0, stream>>>(l1_b1, l1_bn_g, l1_bn_b, l1_bn_m, l1_bn_v, s_l1a, t_l1a, HID, HID_P);
        dim3 s2g((EMB_P + 255) / 256, 1);
        convert_st<<<s2g, 256, 0, stream>>>(l1_b2, l1_bno_g, l1_bno_b, l1_bno_m, l1_bno_v, s_l1b, t_l1b, EMB, EMB_P);
        dim3 s3g((HID_P + 255) / 256, 4);
        convert_st<<<s3g, 256, 0, stream>>>(bs1, bn_g, bn_b, bn_m, bn_v, s1, t1, HID, HID_P);
        dim3 s4g((EMB_P + 255) / 256, 4);
        convert_st<<<s4g, 256, 0, stream>>>(bs2, bno_g, bno_b, bno_m, bno_v, s2, t2, EMB, EMB_P);
    }

    const int gm = M_P / 128;                    // 391
    dim3 gridA(gm, HID_P / 128);                 // N=640
    dim3 gridB(gm, EMB_P / 128);                 // N=384

    // ---- layer 1 ----
    aggregate_f32in<<<(N * 16 + 255) / 256, 256, 0, stream>>>(x, rowptr, esrc, zin);
    gemm_f16_mfma<<<gridA, 256, 0, stream>>>(zin, wt_l1a, s_l1a, t_l1a, zmid, IN_DIM, HID_P, 1);
    gemm_f16_mfma<<<gridB, 256, 0, stream>>>(zmid, wt_l1b, s_l1b, t_l1b, hbuf, HID_P, EMB_P, 1);

    // ---- layers 2..5 ----
    for (int i = 0; i < 4; ++i) {
        aggregate_f16<<<(N * (EMB_K / 8) + 255) / 256, 256, 0, stream>>>(hbuf, rowptr, esrc, zin);
        gemm_f16_mfma<<<gridA, 256, 0, stream>>>(
            zin, wt1 + (size_t)i * HID_P * EMB_K, s1 + i * HID_P, t1 + i * HID_P,
            zmid, EMB_K, HID_P, 1);
        gemm_f16_mfma<<<gridB, 256, 0, stream>>>(
            zmid, wt2 + (size_t)i * EMB_P * HID_P, s2 + i * EMB_P, t2 + i * EMB_P,
            hbuf, HID_P, EMB_P, (i != 3) ? 1 : 0);
    }

    // ---- pool + classify ----
    pool_classify<<<N_GRAPHS, 64, 0, stream>>>(hbuf, batch, clfW, clfb, out, N);
}

// Round 5
// 707.362 us; speedup vs baseline: 6.7562x; 1.0517x over previous
//
#include <hip/hip_runtime.h>
#include <hip/hip_bf16.h>

// ---------------------------------------------------------------------------
// GIN forward, round 5:
//   - GEMM templated on K (64/320/640): fully-unrolled K-loop, compile-time
//     buffer indices -> all global-load offsets / ds_read offsets become
//     immediates, no per-iter VALU address math.
//   - 1-D grid + bijective XCD-chunk swizzle, N-tile fastest: the 3-5 blocks
//     sharing one A-tile run consecutively on the SAME XCD -> A read from L2
//     instead of HBM (round-4 FETCH 96.5 MB vs 64.5 ideal).
//   - unchanged: 3-buf vmcnt(8/4/0) pipeline, fragment-order LDS (0 bank
//     conflicts), CSR build, aggregates, pool.
// ---------------------------------------------------------------------------

#define N_NODES 50000
#define M_P     50048      // 391 * 128
#define N_EDGES 200000
#define IN_DIM  64
#define EMB     300
#define HID     600
#define EMB_P   384        // hbuf row stride / GEMM2 N (3 * 128)
#define EMB_K   320        // zin row stride / GEMM1 K (10 * 32)
#define HID_P   640        // 5 * 128
#define N_GRAPHS 1024
#define N_CLASS 10
#define BN_EPS  1e-5f

typedef _Float16 half8 __attribute__((ext_vector_type(8)));
typedef float    f32x4 __attribute__((ext_vector_type(4)));

__device__ __forceinline__ void gload16(const void* g, void* l) {
    __builtin_amdgcn_global_load_lds(
        (const __attribute__((address_space(1))) void*)g,
        (__attribute__((address_space(3))) void*)l, 16, 0, 0);
}

// ---------------- CSR build ----------------

__global__ void count_deg_kernel(const int* __restrict__ dst, int* __restrict__ deg, int E) {
    int e = blockIdx.x * blockDim.x + threadIdx.x;
    if (e < E) atomicAdd(&deg[dst[e]], 1);
}

__global__ void block_reduce_kernel(const int* __restrict__ in, int* __restrict__ partials, int n) {
    __shared__ int sm[4];
    const int b = blockIdx.x, t = threadIdx.x;
    const int base = b * 1024;
    int v = 0;
    #pragma unroll
    for (int i = 0; i < 4; ++i) {
        int ix = base + t + i * 256;
        if (ix < n) v += in[ix];
    }
    #pragma unroll
    for (int off = 32; off > 0; off >>= 1) v += __shfl_xor(v, off);
    if ((t & 63) == 0) sm[t >> 6] = v;
    __syncthreads();
    if (t == 0) partials[b] = sm[0] + sm[1] + sm[2] + sm[3];
}

__global__ void scan_partials_kernel(int* __restrict__ partials, int nb) {
    const int t = threadIdx.x;
    int v = (t < nb) ? partials[t] : 0;
    const int orig = v;
    #pragma unroll
    for (int off = 1; off < 64; off <<= 1) {
        int u = __shfl_up(v, off);
        if (t >= off) v += u;
    }
    if (t < nb) partials[t] = v - orig;
}

__global__ void block_scan_kernel(const int* __restrict__ in, const int* __restrict__ partials,
                                  int* __restrict__ out, int n, int total) {
    __shared__ int sd[1024];
    const int b = blockIdx.x, t = threadIdx.x;
    const int idx = b * 1024 + t;
    const int v = (idx < n) ? in[idx] : 0;
    sd[t] = v;
    __syncthreads();
    #pragma unroll
    for (int off = 1; off < 1024; off <<= 1) {
        int u = (t >= off) ? sd[t - off] : 0;
        __syncthreads();
        sd[t] += u;
        __syncthreads();
    }
    if (idx < n) out[idx] = partials[b] + sd[t] - v;
    if (b == 0 && t == 0) out[n] = total;
}

__global__ void scatter_edges_kernel(const int* __restrict__ src, const int* __restrict__ dst,
                                     int* __restrict__ cursor, int* __restrict__ esrc, int E) {
    int e = blockIdx.x * blockDim.x + threadIdx.x;
    if (e < E) {
        int d = dst[e];
        int pos = atomicAdd(&cursor[d], 1);
        esrc[pos] = src[e];
    }
}

// ---------------- weight / epilogue-param conversion ----------------

__global__ void convert_w(const float* __restrict__ W, _Float16* __restrict__ Wt,
                          int K, int N, int K_P, int N_P) {
    int b = blockIdx.y;
    int i = blockIdx.x * 256 + threadIdx.x;
    if (i >= N_P * K_P) return;
    int n = i / K_P, k = i % K_P;
    _Float16 v = (_Float16)0.f;
    if (n < N && k < K) v = (_Float16)W[((size_t)b * K + k) * N + n];
    Wt[(size_t)b * N_P * K_P + i] = v;
}

__global__ void convert_st(const float* __restrict__ bias, const float* __restrict__ g,
                           const float* __restrict__ bb, const float* __restrict__ m,
                           const float* __restrict__ v, float* __restrict__ S,
                           float* __restrict__ T, int N, int N_P) {
    int b = blockIdx.y;
    int i = blockIdx.x * 256 + threadIdx.x;
    if (i >= N_P) return;
    float s = 0.f, t = 0.f;
    if (i < N) {
        s = g[b * N + i] * rsqrtf(v[b * N + i] + BN_EPS);
        t = (bias[b * N + i] - m[b * N + i]) * s + bb[b * N + i];
    }
    S[b * N_P + i] = s;
    T[b * N_P + i] = t;
}

// ---------------- aggregation ----------------

__global__ void aggregate_f16(const _Float16* __restrict__ h, const int* __restrict__ rowptr,
                              const int* __restrict__ esrc, _Float16* __restrict__ z) {
    const int NCH = EMB_K / 8;          // 40
    const int NACT = 38;                // ceil(300/8); h cols 300..383 are 0
    int t = blockIdx.x * blockDim.x + threadIdx.x;
    int node = t / NCH;
    int c = t - node * NCH;
    if (node >= N_NODES) return;
    _Float16* zp = z + (size_t)node * EMB_K + c * 8;
    if (c >= NACT) {
        half8 zero = {};
        *(half8*)zp = zero;
        return;
    }
    float a[8];
    half8 v = *(const half8*)(h + (size_t)node * EMB_P + c * 8);
    #pragma unroll
    for (int j = 0; j < 8; ++j) a[j] = (float)v[j];
    int s0 = rowptr[node], s1 = rowptr[node + 1];
    for (int e = s0; e < s1; ++e) {
        half8 u = *(const half8*)(h + (size_t)esrc[e] * EMB_P + c * 8);
        #pragma unroll
        for (int j = 0; j < 8; ++j) a[j] += (float)u[j];
    }
    half8 o;
    #pragma unroll
    for (int j = 0; j < 8; ++j) o[j] = (_Float16)a[j];
    *(half8*)zp = o;
}

__global__ void aggregate_f32in(const float* __restrict__ x, const int* __restrict__ rowptr,
                                const int* __restrict__ esrc, _Float16* __restrict__ z) {
    int t = blockIdx.x * blockDim.x + threadIdx.x;
    int node = t >> 4;
    int c = t & 15;
    if (node >= N_NODES) return;
    float4 a = *(const float4*)(x + (size_t)node * IN_DIM + c * 4);
    int s0 = rowptr[node], s1 = rowptr[node + 1];
    for (int e = s0; e < s1; ++e) {
        float4 u = *(const float4*)(x + (size_t)esrc[e] * IN_DIM + c * 4);
        a.x += u.x; a.y += u.y; a.z += u.z; a.w += u.w;
    }
    _Float16* zp = z + (size_t)node * IN_DIM + c * 4;
    zp[0] = (_Float16)a.x; zp[1] = (_Float16)a.y;
    zp[2] = (_Float16)a.z; zp[3] = (_Float16)a.w;
}

// ---------------- GEMM: C[M_P][NP] = epi(A[M_P][KP] @ Bt^T), f16 MFMA ----------------
// Templated on KP -> fully unrolled K-loop, static buffer indices/offsets.
// LDS: 3 bufs x (A 128x32 + B 128x32) in MFMA fragment order (0 conflicts).
// 1-D grid, bijective XCD-chunk swizzle, N-tile fastest (A-tile L2 reuse).

template<int KP>
__global__ __launch_bounds__(256) void gemm_f16_mfma(
        const _Float16* __restrict__ A, const _Float16* __restrict__ Bt,
        const float* __restrict__ Sc, const float* __restrict__ Tc,
        _Float16* __restrict__ C, int N_P, int do_relu) {
    constexpr int NT = KP / 32;
    __shared__ _Float16 As[3 * 4096];
    __shared__ _Float16 Bs[3 * 4096];
    const int tid  = threadIdx.x;
    const int wid  = tid >> 6;
    const int lane = tid & 63;

    // bijective XCD-chunk swizzle (m204): consecutive wgid -> same XCD;
    // wgid decodes n fastest so same-A blocks are adjacent on one XCD.
    const int NY  = N_P >> 7;
    const int nwg = gridDim.x;
    {
    }
    const int q = nwg >> 3, r = nwg & 7;
    const int xcd = blockIdx.x & 7, idx = blockIdx.x >> 3;
    const int wgid = (xcd < r ? xcd * (q + 1) : r * (q + 1) + (xcd - r) * q) + idx;
    const int mt = wgid / NY;
    const int nt_ = wgid - mt * NY;
    const size_t bm0 = (size_t)mt * 128;
    const int    bn0 = nt_ * 128;

    const int wr = (wid >> 1) * 64;
    const int wc = (wid & 1) * 64;

    // staging: lane l -> row_local l&15, k-slot l>>4 (fragment order)
    const int srow = lane & 15;
    const int scol = (lane >> 4) * 8;
    const _Float16* gA0 = A  + (bm0 + wid * 16 + srow) * (size_t)KP + scol;
    const _Float16* gA1 = gA0 + (size_t)64 * KP;
    const _Float16* gB0 = Bt + ((size_t)bn0 + wid * 16 + srow) * (size_t)KP + scol;
    const _Float16* gB1 = gB0 + (size_t)64 * KP;
    _Float16* lA0 = As + wid * 512;          // subtile wid
    _Float16* lA1 = As + (wid + 4) * 512;    // subtile wid+4
    _Float16* lB0 = Bs + wid * 512;
    _Float16* lB1 = Bs + (wid + 4) * 512;

    f32x4 acc[4][4];
    #pragma unroll
    for (int m = 0; m < 4; ++m)
        #pragma unroll
        for (int n = 0; n < 4; ++n) acc[m][n] = (f32x4){0.f, 0.f, 0.f, 0.f};

    const int subA = (wr >> 4);              // 0 or 4
    const int subB = (wc >> 4);

    #pragma unroll
    for (int p = 0; p < 2 && p < NT; ++p) {  // prologue: stages 0,1
        const int o = p * 4096, k0 = p * 32;
        gload16(gA0 + k0, lA0 + o);
        gload16(gA1 + k0, lA1 + o);
        gload16(gB0 + k0, lB0 + o);
        gload16(gB1 + k0, lB1 + o);
    }

    #pragma unroll
    for (int t = 0; t < NT; ++t) {
        if (t + 2 < NT) {                    // stage t+2 (buffer static)
            const int b = (t + 2) % 3;
            const int o = b * 4096, k0 = (t + 2) * 32;
            gload16(gA0 + k0, lA0 + o);
            gload16(gA1 + k0, lA1 + o);
            gload16(gB0 + k0, lB0 + o);
            gload16(gB1 + k0, lB1 + o);
        }
        if (t + 2 < NT)      asm volatile("s_waitcnt vmcnt(8)" ::: "memory");
        else if (t + 1 < NT) asm volatile("s_waitcnt vmcnt(4)" ::: "memory");
        else                 asm volatile("s_waitcnt vmcnt(0)" ::: "memory");
        __builtin_amdgcn_s_barrier();
        {
            const _Float16* as = As + (t % 3) * 4096;
            const _Float16* bs = Bs + (t % 3) * 4096;
            half8 af[4], bf[4];
            #pragma unroll
            for (int m = 0; m < 4; ++m)
                af[m] = *(const half8*)(as + (subA + m) * 512 + lane * 8);
            #pragma unroll
            for (int n = 0; n < 4; ++n)
                bf[n] = *(const half8*)(bs + (subB + n) * 512 + lane * 8);
            #pragma unroll
            for (int m = 0; m < 4; ++m)
                #pragma unroll
                for (int n = 0; n < 4; ++n)
                    acc[m][n] = __builtin_amdgcn_mfma_f32_16x16x32_f16(af[m], bf[n], acc[m][n], 0, 0, 0);
        }
        if (t + 1 < NT) __builtin_amdgcn_s_barrier();
    }

    // epilogue: y = acc*S[col] + T[col] (+ReLU), store f16
    #pragma unroll
    for (int n = 0; n < 4; ++n) {
        const int col = bn0 + wc + n * 16 + (lane & 15);
        const float s = Sc[col], t = Tc[col];
        #pragma unroll
        for (int m = 0; m < 4; ++m) {
            f32x4 v = acc[m][n];
            const size_t rbase = bm0 + wr + m * 16 + (lane >> 4) * 4;
            #pragma unroll
            for (int r = 0; r < 4; ++r) {
                float y = v[r] * s + t;
                if (do_relu) y = fmaxf(y, 0.f);
                C[(rbase + r) * (size_t)N_P + col] = (_Float16)y;
            }
        }
    }
}

// ---------------- mean pool + classifier ----------------

__global__ void pool_classify(const _Float16* __restrict__ h, const int* __restrict__ batch,
                              const float* __restrict__ clfW, const float* __restrict__ clfb,
                              float* __restrict__ out, int n) {
    int g = blockIdx.x;
    __shared__ int s_lo, s_hi;
    __shared__ float pooled[304];
    if (threadIdx.x == 0) {
        int lo = 0, hi = n;
        while (lo < hi) { int mid = (lo + hi) >> 1; if (batch[mid] < g) lo = mid + 1; else hi = mid; }
        s_lo = lo;
        int lo2 = lo, hi2 = n;
        while (lo2 < hi2) { int mid = (lo2 + hi2) >> 1; if (batch[mid] < g + 1) lo2 = mid + 1; else hi2 = mid; }
        s_hi = lo2;
    }
    __syncthreads();
    const int lo = s_lo, hi = s_hi;
    const float inv = 1.0f / fmaxf((float)(hi - lo), 1.0f);
    const int c = threadIdx.x;
    if (c < 38) {
        float a[8] = {0.f, 0.f, 0.f, 0.f, 0.f, 0.f, 0.f, 0.f};
        for (int r = lo; r < hi; ++r) {
            half8 v = *(const half8*)(h + (size_t)r * EMB_P + c * 8);
            #pragma unroll
            for (int j = 0; j < 8; ++j) a[j] += (float)v[j];
        }
        #pragma unroll
        for (int j = 0; j < 8; ++j) pooled[c * 8 + j] = a[j] * inv;
    }
    __syncthreads();
    const int lane = threadIdx.x & 63;
    for (int cc = 0; cc < N_CLASS; ++cc) {
        float p = 0.f;
        for (int d = lane; d < EMB; d += 64) p += pooled[d] * clfW[d * N_CLASS + cc];
        #pragma unroll
        for (int off = 32; off > 0; off >>= 1) p += __shfl_down(p, off);
        if (lane == 0) out[g * N_CLASS + cc] = p + clfb[cc];
    }
}

// ---------------- launch ----------------

extern "C" void kernel_launch(void* const* d_in, const int* in_sizes, int n_in,
                              void* d_out, int out_size, void* d_ws, size_t ws_size,
                              hipStream_t stream) {
    const float* x      = (const float*)d_in[0];
    const int*   ei     = (const int*)d_in[1];
    const int*   batch  = (const int*)d_in[2];
    const float* l1_W1  = (const float*)d_in[3];
    const float* l1_b1  = (const float*)d_in[4];
    const float* l1_bn_g = (const float*)d_in[5];
    const float* l1_bn_b = (const float*)d_in[6];
    const float* l1_bn_m = (const float*)d_in[7];
    const float* l1_bn_v = (const float*)d_in[8];
    const float* l1_W2  = (const float*)d_in[9];
    const float* l1_b2  = (const float*)d_in[10];
    const float* l1_bno_g = (const float*)d_in[11];
    const float* l1_bno_b = (const float*)d_in[12];
    const float* l1_bno_m = (const float*)d_in[13];
    const float* l1_bno_v = (const float*)d_in[14];
    const float* Ws1    = (const float*)d_in[15];
    const float* bs1    = (const float*)d_in[16];
    const float* bn_g   = (const float*)d_in[17];
    const float* bn_b   = (const float*)d_in[18];
    const float* bn_m   = (const float*)d_in[19];
    const float* bn_v   = (const float*)d_in[20];
    const float* Ws2    = (const float*)d_in[21];
    const float* bs2    = (const float*)d_in[22];
    const float* bno_g  = (const float*)d_in[23];
    const float* bno_b  = (const float*)d_in[24];
    const float* bno_m  = (const float*)d_in[25];
    const float* bno_v  = (const float*)d_in[26];
    const float* clfW   = (const float*)d_in[27];
    const float* clfb   = (const float*)d_in[28];
    float* out = (float*)d_out;

    const int N = N_NODES, E = N_EDGES;
    const int* src = ei;
    const int* dst = ei + E;

    char* ws = (char*)d_ws;
    size_t off = 0;
    auto alloc = [&](size_t bytes) -> void* {
        void* p = ws + off;
        off += (bytes + 255) & ~(size_t)255;
        return p;
    };
    _Float16* zmid  = (_Float16*)alloc((size_t)M_P * HID_P * 2);   // 64 MB
    _Float16* hbuf  = (_Float16*)alloc((size_t)M_P * EMB_P * 2);   // 38 MB
    _Float16* zin   = (_Float16*)alloc((size_t)M_P * EMB_K * 2);   // 32 MB
    _Float16* wt_l1a = (_Float16*)alloc((size_t)HID_P * IN_DIM * 2);
    _Float16* wt_l1b = (_Float16*)alloc((size_t)EMB_P * HID_P * 2);
    _Float16* wt1   = (_Float16*)alloc((size_t)4 * HID_P * EMB_K * 2);
    _Float16* wt2   = (_Float16*)alloc((size_t)4 * EMB_P * HID_P * 2);
    float* s_l1a = (float*)alloc(HID_P * 4); float* t_l1a = (float*)alloc(HID_P * 4);
    float* s_l1b = (float*)alloc(EMB_P * 4); float* t_l1b = (float*)alloc(EMB_P * 4);
    float* s1 = (float*)alloc(4 * HID_P * 4); float* t1 = (float*)alloc(4 * HID_P * 4);
    float* s2 = (float*)alloc(4 * EMB_P * 4); float* t2 = (float*)alloc(4 * EMB_P * 4);
    int* deg      = (int*)alloc((size_t)N * 4);
    int* rowptr   = (int*)alloc((size_t)(N + 1) * 4);
    int* cursor   = (int*)alloc((size_t)N * 4);
    int* esrc     = (int*)alloc((size_t)E * 4);
    int* partials = (int*)alloc(64 * 4);
    (void)ws_size; (void)n_in; (void)in_sizes; (void)out_size;

    const int NB_SCAN = (N + 1023) / 1024;   // 49

    // ---- CSR ----
    hipMemsetAsync(deg, 0, (size_t)N * 4, stream);
    count_deg_kernel<<<(E + 255) / 256, 256, 0, stream>>>(dst, deg, E);
    block_reduce_kernel<<<NB_SCAN, 256, 0, stream>>>(deg, partials, N);
    scan_partials_kernel<<<1, 64, 0, stream>>>(partials, NB_SCAN);
    block_scan_kernel<<<NB_SCAN, 1024, 0, stream>>>(deg, partials, rowptr, N, E);
    hipMemcpyAsync(cursor, rowptr, (size_t)N * 4, hipMemcpyDeviceToDevice, stream);
    scatter_edges_kernel<<<(E + 255) / 256, 256, 0, stream>>>(src, dst, cursor, esrc, E);

    // ---- weight & epilogue-param conversion ----
    {
        dim3 g1((HID_P * IN_DIM + 255) / 256, 1);
        convert_w<<<g1, 256, 0, stream>>>(l1_W1, wt_l1a, IN_DIM, HID, IN_DIM, HID_P);
        dim3 g2((EMB_P * HID_P + 255) / 256, 1);
        convert_w<<<g2, 256, 0, stream>>>(l1_W2, wt_l1b, HID, EMB, HID_P, EMB_P);
        dim3 g3((HID_P * EMB_K + 255) / 256, 4);
        convert_w<<<g3, 256, 0, stream>>>(Ws1, wt1, EMB, HID, EMB_K, HID_P);
        dim3 g4((EMB_P * HID_P + 255) / 256, 4);
        convert_w<<<g4, 256, 0, stream>>>(Ws2, wt2, HID, EMB, HID_P, EMB_P);

        dim3 s1g((HID_P + 255) / 256, 1);
        convert_st<<<s1g, 256, 0, stream>>>(l1_b1, l1_bn_g, l1_bn_b, l1_bn_m, l1_bn_v, s_l1a, t_l1a, HID, HID_P);
        dim3 s2g((EMB_P + 255) / 256, 1);
        convert_st<<<s2g, 256, 0, stream>>>(l1_b2, l1_bno_g, l1_bno_b, l1_bno_m, l1_bno_v, s_l1b, t_l1b, EMB, EMB_P);
        dim3 s3g((HID_P + 255) / 256, 4);
        convert_st<<<s3g, 256, 0, stream>>>(bs1, bn_g, bn_b, bn_m, bn_v, s1, t1, HID, HID_P);
        dim3 s4g((EMB_P + 255) / 256, 4);
        convert_st<<<s4g, 256, 0, stream>>>(bs2, bno_g, bno_b, bno_m, bno_v, s2, t2, EMB, EMB_P);
    }

    const int gm = M_P / 128;                    // 391
    const int gA = gm * (HID_P / 128);           // 1955 blocks, N=640
    const int gB = gm * (EMB_P / 128);           // 1173 blocks, N=384

    // ---- layer 1 ----
    aggregate_f32in<<<(N * 16 + 255) / 256, 256, 0, stream>>>(x, rowptr, esrc, zin);
    gemm_f16_mfma<64><<<gA, 256, 0, stream>>>(zin, wt_l1a, s_l1a, t_l1a, zmid, HID_P, 1);
    gemm_f16_mfma<640><<<gB, 256, 0, stream>>>(zmid, wt_l1b, s_l1b, t_l1b, hbuf, EMB_P, 1);

    // ---- layers 2..5 ----
    for (int i = 0; i < 4; ++i) {
        aggregate_f16<<<(N * (EMB_K / 8) + 255) / 256, 256, 0, stream>>>(hbuf, rowptr, esrc, zin);
        gemm_f16_mfma<320><<<gA, 256, 0, stream>>>(
            zin, wt1 + (size_t)i * HID_P * EMB_K, s1 + i * HID_P, t1 + i * HID_P,
            zmid, HID_P, 1);
        gemm_f16_mfma<640><<<gB, 256, 0, stream>>>(
            zmid, wt2 + (size_t)i * EMB_P * HID_P, s2 + i * EMB_P, t2 + i * EMB_P,
            hbuf, EMB_P, (i != 3) ? 1 : 0);
    }

    // ---- pool + classify ----
    pool_classify<<<N_GRAPHS, 64, 0, stream>>>(hbuf, batch, clfW, clfb, out, N);
}